// Round 9
// baseline (487.018 us; speedup 1.0000x reference)
//
#include <hip/hip_runtime.h>
#include <stdint.h>

#define NN 100000
#define NE 1600000
#define NG 1000
#define FIN 128
#define DIM 32
#define NC 10

#define NBKT 512          // super-buckets over dst nodes
#define NPB 196           // nodes per bucket (512*196 = 100352 >= NN)
#define BCAP 4096         // edges per bucket (mean 3136 + <=196 pad, ~10 sigma headroom)
#define RND 2048          // edges per binning block
#define CURS 16           // cursor stride in ints (one per 64-B line)

typedef unsigned int u32;
typedef __attribute__((ext_vector_type(8))) short short8;
typedef __attribute__((ext_vector_type(4))) float floatx4;
typedef __attribute__((ext_vector_type(4))) unsigned int uint4e;   // vector-of-int: nontemporal-builtin legal

__device__ __forceinline__ ushort f2bf(float f) {
    u32 b = __float_as_uint(f);
    return (ushort)((b + 0x7FFFu + ((b >> 16) & 1u)) >> 16);   // RNE
}
__device__ __forceinline__ float bf2f(ushort u) {
    return __uint_as_float(((u32)u) << 16);
}

// ---------------- zero ----------------
__global__ void k_zero(u32* __restrict__ p, int n) {
    int i = blockIdx.x * blockDim.x + threadIdx.x;
    if (i < n) p[i] = 0u;
}

// ---------------- binning: edges -> 512 dst-super-buckets, LDS write-combined ----------------
__global__ __launch_bounds__(256) void k_bin(const int* __restrict__ ei,
        const float* __restrict__ ew, int* __restrict__ cursor,
        uint2* __restrict__ ebuf) {
    __shared__ uint2  ent[RND];
    __shared__ ushort bk16[RND];
    __shared__ int cnt[NBKT];
    __shared__ int sA[NBKT];
    __shared__ int sB[NBKT];
    __shared__ int gbase[NBKT];
    int tid = threadIdx.x;
    int e0 = blockIdx.x * RND;
    int n  = min(RND, NE - e0);
    if (n <= 0) return;

    for (int i = tid; i < NBKT; i += 256) cnt[i] = 0;
    __syncthreads();

    u32 pk[8], wv[8], bp[8];
    #pragma unroll
    for (int q = 0; q < 8; ++q) {
        int i = tid + q * 256;
        pk[q] = 0; wv[q] = 0; bp[q] = 0;
        if (i < n) {
            int s = ei[e0 + i];
            int d = ei[NE + e0 + i];
            float w = ew[e0 + i];
            int b = d / NPB;
            int loc = d - b * NPB;
            int p = atomicAdd(&cnt[b], 1);
            pk[q] = (u32)s | ((u32)loc << 17);
            wv[q] = __float_as_uint(w);
            bp[q] = (u32)p | ((u32)b << 16);
        }
    }
    __syncthreads();

    for (int i = tid; i < NBKT; i += 256) sA[i] = cnt[i];
    __syncthreads();
    int* ssrc = sA; int* sdst = sB;
    for (int dd = 1; dd < NBKT; dd <<= 1) {
        for (int i = tid; i < NBKT; i += 256)
            sdst[i] = ssrc[i] + (i >= dd ? ssrc[i - dd] : 0);
        __syncthreads();
        int* t = ssrc; ssrc = sdst; sdst = t;
    }
    for (int i = tid; i < NBKT; i += 256) {
        int excl = ssrc[i] - cnt[i];
        sdst[i] = excl;
        if (cnt[i] > 0) gbase[i] = atomicAdd(&cursor[i * CURS], cnt[i]);
    }
    __syncthreads();
    int* basep = sdst;

    #pragma unroll
    for (int q = 0; q < 8; ++q) {
        int i = tid + q * 256;
        if (i < n) {
            int b = (int)(bp[q] >> 16);
            int p = (int)(bp[q] & 0xFFFFu);
            int pos = basep[b] + p;
            ent[pos]  = make_uint2(pk[q], wv[q]);
            bk16[pos] = (ushort)b;
        }
    }
    __syncthreads();

    for (int i = tid; i < n; i += 256) {
        int b = (int)bk16[i];
        int dsti = gbase[b] + (i - basep[b]);
        if (dsti < BCAP) ebuf[(size_t)b * BCAP + dsti] = ent[i];
    }
}

// ---------------- CSR: counting-sort each bucket by local node; segments padded to even
//                  (16-B aligned) starts, pads zero-filled; emit (off,deg) ----------------
__global__ __launch_bounds__(256) void k_csr(uint2* __restrict__ ebuf,
        const int* __restrict__ cursor, uint2* __restrict__ od) {
    __shared__ uint2 ent[BCAP];      // 32 KB
    __shared__ int hist[NPB];
    __shared__ int sc[NPB];
    __shared__ int base[NPB];
    int tid = threadIdx.x;
    int bkt = blockIdx.x;
    int cnt = min(cursor[bkt * CURS], BCAP);
    for (int i = tid; i < NPB; i += 256) hist[i] = 0;
    __syncthreads();
    uint2* gb = ebuf + (size_t)bkt * BCAP;
    uint2 my[16]; int mp[16];
    #pragma unroll
    for (int q = 0; q < 16; ++q) {
        int i = tid + q * 256;
        mp[q] = -1;
        if (i < cnt) {
            my[q] = gb[i];
            int loc = (int)(my[q].x >> 17);
            mp[q] = atomicAdd(&hist[loc], 1);
        }
    }
    __syncthreads();
    // inclusive scan of even-padded sizes
    for (int i = tid; i < NPB; i += 256) sc[i] = (hist[i] + 1) & ~1;
    __syncthreads();
    for (int dd = 1; dd < NPB; dd <<= 1) {
        int v = 0;
        if (tid < NPB) { v = sc[tid]; if (tid >= dd) v += sc[tid - dd]; }
        __syncthreads();
        if (tid < NPB) sc[tid] = v;
        __syncthreads();
    }
    for (int i = tid; i < NPB; i += 256) base[i] = sc[i] - ((hist[i] + 1) & ~1);
    __syncthreads();
    int tot = min(sc[NPB - 1], BCAP);
    for (int i = tid; i < tot; i += 256) ent[i] = make_uint2(0u, 0u);  // zero pads
    __syncthreads();
    #pragma unroll
    for (int q = 0; q < 16; ++q) {
        if (mp[q] >= 0) {
            int loc = (int)(my[q].x >> 17);
            int pos = base[loc] + mp[q];
            if (pos < BCAP) ent[pos] = my[q];
        }
    }
    __syncthreads();
    for (int i = tid; i < tot; i += 256) gb[i] = ent[i];
    for (int i = tid; i < NPB; i += 256) {
        int node = bkt * NPB + i;
        if (node < NN) {
            int dg = hist[i];
            if (base[i] + dg > BCAP) dg = max(0, BCAP - base[i]);   // statistically never
            od[node] = make_uint2((u32)(bkt * BCAP + base[i]), (u32)dg);
        }
    }
}

// ---------------- layer-1 matmul via bf16 MFMA ----------------
__global__ __launch_bounds__(256) void k_mm1(const float* __restrict__ x,
        const float* __restrict__ Wrel, const float* __restrict__ brel,
        const float* __restrict__ Wroot,
        ushort* __restrict__ ybf, float* __restrict__ aggi) {
    __shared__ ushort xs[64 * 136];
    int tid = threadIdx.x;
    int base = blockIdx.x * 64;
    for (int i = tid; i < 64 * 32; i += 256) {
        int r = i >> 5, c = i & 31;
        int node = base + r;
        float4 v = make_float4(0.f, 0.f, 0.f, 0.f);
        if (node < NN) v = ((const float4*)x)[(size_t)node * 32 + c];
        ushort4 u;
        u.x = f2bf(v.x); u.y = f2bf(v.y); u.z = f2bf(v.z); u.w = f2bf(v.w);
        *(ushort4*)&xs[r * 136 + c * 4] = u;
    }
    int lane = tid & 63;
    int w = tid >> 6;
    int m = lane & 15;
    int q = lane >> 4;
    short8 bfr[4][4];
    #pragma unroll
    for (int nt = 0; nt < 4; ++nt) {
        const float* W = (nt < 2) ? Wrel : Wroot;
        int ncol = (nt & 1) * 16 + m;
        #pragma unroll
        for (int kc = 0; kc < 4; ++kc) {
            short8 fr;
            #pragma unroll
            for (int j = 0; j < 8; ++j) {
                int k = kc * 32 + q * 8 + j;
                fr[j] = (short)f2bf(W[k * 32 + ncol]);
            }
            bfr[nt][kc] = fr;
        }
    }
    __syncthreads();
    floatx4 acc[4] = {{0.f,0.f,0.f,0.f},{0.f,0.f,0.f,0.f},{0.f,0.f,0.f,0.f},{0.f,0.f,0.f,0.f}};
    #pragma unroll
    for (int kc = 0; kc < 4; ++kc) {
        short8 af = *(const short8*)&xs[(w * 16 + m) * 136 + kc * 32 + q * 8];
        #pragma unroll
        for (int nt = 0; nt < 4; ++nt)
            acc[nt] = __builtin_amdgcn_mfma_f32_16x16x32_bf16(af, bfr[nt][kc], acc[nt], 0, 0, 0);
    }
    float br0 = brel[m], br1 = brel[16 + m];
    #pragma unroll
    for (int reg = 0; reg < 4; ++reg) {
        int row = q * 4 + reg;
        int node = base + w * 16 + row;
        if (node < NN) {
            ybf[(size_t)node * 32 + m]       = f2bf(acc[0][reg]);
            ybf[(size_t)node * 32 + 16 + m]  = f2bf(acc[1][reg]);
            aggi[(size_t)node * 32 + m]      = acc[2][reg] + br0;
            aggi[(size_t)node * 32 + 16 + m] = acc[3][reg] + br1;
        }
    }
}

// ---------------- layers 2-5 matmul (fp32 vector; K=32 small) ----------------
__global__ __launch_bounds__(256) void k_mm_small(const float* __restrict__ in,
        const float* __restrict__ Wrel, const float* __restrict__ brel,
        const float* __restrict__ Wroot,
        ushort* __restrict__ ybf, float* __restrict__ aggi) {
    __shared__ float wr[DIM * DIM];
    __shared__ float wo[DIM * DIM];
    __shared__ float hs[128 * 36];
    int tid = threadIdx.x;
    for (int i = tid; i < DIM * DIM / 4; i += 256) {
        ((float4*)wr)[i] = ((const float4*)Wrel)[i];
        ((float4*)wo)[i] = ((const float4*)Wroot)[i];
    }
    int l  = tid & 7;
    int ng = tid >> 3;
    int base = blockIdx.x * 128;
    float4 b4 = ((const float4*)brel)[l];
    __syncthreads();
    for (int i = tid; i < 1024; i += 256) {
        int r = i >> 3, c = i & 7;
        int node = base + r;
        float4 v = make_float4(0.f, 0.f, 0.f, 0.f);
        if (node < NN) {
            v = ((const float4*)in)[(size_t)node * 8 + c];
            v.x = fmaxf(v.x, 0.f); v.y = fmaxf(v.y, 0.f);
            v.z = fmaxf(v.z, 0.f); v.w = fmaxf(v.w, 0.f);
        }
        ((float4*)hs)[r * 9 + c] = v;
    }
    __syncthreads();
    float4 aR[4], aO[4];
    #pragma unroll
    for (int r = 0; r < 4; ++r) {
        aR[r] = make_float4(0.f, 0.f, 0.f, 0.f);
        aO[r] = b4;
    }
    #pragma unroll 4
    for (int k = 0; k < DIM; ++k) {
        float4 w1 = ((float4*)wr)[k * 8 + l];
        float4 w2 = ((float4*)wo)[k * 8 + l];
        #pragma unroll
        for (int r = 0; r < 4; ++r) {
            float hv = hs[(ng + 32 * r) * 36 + k];
            aR[r].x += hv * w1.x; aR[r].y += hv * w1.y;
            aR[r].z += hv * w1.z; aR[r].w += hv * w1.w;
            aO[r].x += hv * w2.x; aO[r].y += hv * w2.y;
            aO[r].z += hv * w2.z; aO[r].w += hv * w2.w;
        }
    }
    #pragma unroll
    for (int r = 0; r < 4; ++r) {
        int node = base + ng + 32 * r;
        if (node < NN) {
            ushort4 yo;
            yo.x = f2bf(aR[r].x); yo.y = f2bf(aR[r].y);
            yo.z = f2bf(aR[r].z); yo.w = f2bf(aR[r].w);
            ((ushort4*)ybf)[(size_t)node * 8 + l] = yo;
            ((float4*)aggi)[(size_t)node * 8 + l] = aO[r];
        }
    }
}

// ---------------- gather: CSR, uint4 entry loads, ~24 loads in flight ----------------
__global__ __launch_bounds__(256, 6) void k_gather(const ushort* __restrict__ ybf,
        const uint2* __restrict__ ebuf, const uint2* __restrict__ od,
        float* __restrict__ agg) {
    int tid = threadIdx.x;
    int f = tid & 31;
    int node = blockIdx.x * 8 + (tid >> 5);
    if (node >= NN) return;
    uint2 o = od[node];
    int deg = (int)o.y;
    const uint4e* eb4 = (const uint4e*)(ebuf + o.x);   // o.x even -> 16-B aligned
    const ushort* yb = ybf + f;
    size_t oo = (size_t)node * DIM + f;
    float prev = __builtin_nontemporal_load(&agg[oo]); // overlap RMW-load latency
    float acc0 = 0.f, acc1 = 0.f;
    for (int b = 0; b < deg; b += 16) {
        const uint4e* p = eb4 + (b >> 1);              // 2 entries per uint4 -> 8 uint4 per 16 entries
        uint4e e0 = __builtin_nontemporal_load(p + 0);
        uint4e e1 = __builtin_nontemporal_load(p + 1);
        uint4e e2 = __builtin_nontemporal_load(p + 2);
        uint4e e3 = __builtin_nontemporal_load(p + 3);
        uint4e e4 = __builtin_nontemporal_load(p + 4);
        uint4e e5 = __builtin_nontemporal_load(p + 5);
        uint4e e6 = __builtin_nontemporal_load(p + 6);
        uint4e e7 = __builtin_nontemporal_load(p + 7);
        float y0  = bf2f(yb[(size_t)(e0.x & 0x1FFFFu) * DIM]);
        float y1  = bf2f(yb[(size_t)(e0.z & 0x1FFFFu) * DIM]);
        float y2  = bf2f(yb[(size_t)(e1.x & 0x1FFFFu) * DIM]);
        float y3  = bf2f(yb[(size_t)(e1.z & 0x1FFFFu) * DIM]);
        float y4  = bf2f(yb[(size_t)(e2.x & 0x1FFFFu) * DIM]);
        float y5  = bf2f(yb[(size_t)(e2.z & 0x1FFFFu) * DIM]);
        float y6  = bf2f(yb[(size_t)(e3.x & 0x1FFFFu) * DIM]);
        float y7  = bf2f(yb[(size_t)(e3.z & 0x1FFFFu) * DIM]);
        float y8  = bf2f(yb[(size_t)(e4.x & 0x1FFFFu) * DIM]);
        float y9  = bf2f(yb[(size_t)(e4.z & 0x1FFFFu) * DIM]);
        float y10 = bf2f(yb[(size_t)(e5.x & 0x1FFFFu) * DIM]);
        float y11 = bf2f(yb[(size_t)(e5.z & 0x1FFFFu) * DIM]);
        float y12 = bf2f(yb[(size_t)(e6.x & 0x1FFFFu) * DIM]);
        float y13 = bf2f(yb[(size_t)(e6.z & 0x1FFFFu) * DIM]);
        float y14 = bf2f(yb[(size_t)(e7.x & 0x1FFFFu) * DIM]);
        float y15 = bf2f(yb[(size_t)(e7.z & 0x1FFFFu) * DIM]);
        int r = deg - b;   // pads are zero-entries; tail beyond segment masked by r
        acc0 += (( 0 < r) ? __uint_as_float(e0.y) : 0.f) * y0;
        acc1 += (( 1 < r) ? __uint_as_float(e0.w) : 0.f) * y1;
        acc0 += (( 2 < r) ? __uint_as_float(e1.y) : 0.f) * y2;
        acc1 += (( 3 < r) ? __uint_as_float(e1.w) : 0.f) * y3;
        acc0 += (( 4 < r) ? __uint_as_float(e2.y) : 0.f) * y4;
        acc1 += (( 5 < r) ? __uint_as_float(e2.w) : 0.f) * y5;
        acc0 += (( 6 < r) ? __uint_as_float(e3.y) : 0.f) * y6;
        acc1 += (( 7 < r) ? __uint_as_float(e3.w) : 0.f) * y7;
        acc0 += (( 8 < r) ? __uint_as_float(e4.y) : 0.f) * y8;
        acc1 += (( 9 < r) ? __uint_as_float(e4.w) : 0.f) * y9;
        acc0 += ((10 < r) ? __uint_as_float(e5.y) : 0.f) * y10;
        acc1 += ((11 < r) ? __uint_as_float(e5.w) : 0.f) * y11;
        acc0 += ((12 < r) ? __uint_as_float(e6.y) : 0.f) * y12;
        acc1 += ((13 < r) ? __uint_as_float(e6.w) : 0.f) * y13;
        acc0 += ((14 < r) ? __uint_as_float(e7.y) : 0.f) * y14;
        acc1 += ((15 < r) ? __uint_as_float(e7.w) : 0.f) * y15;
    }
    __builtin_nontemporal_store(prev + acc0 + acc1, &agg[oo]);
}

// ---------------- pool: g[batch[n]] += relu(h[n]); batch sorted ----------------
#define STRIP 32
__global__ __launch_bounds__(256) void k_pool(const float* __restrict__ h,
        const int* __restrict__ batch, float* __restrict__ g) {
    int tid = threadIdx.x;
    int lane = tid & 31;
    int grp = blockIdx.x * 8 + (tid >> 5);
    int start = grp * STRIP;
    if (start >= NN) return;
    int end = min(start + STRIP, NN);
    int curb = batch[start];
    float run = 0.f;
    for (int n = start; n < end; ++n) {
        int b = batch[n];
        if (b != curb) {
            atomicAdd(&g[(size_t)curb * DIM + lane], run);
            run = 0.f; curb = b;
        }
        run += fmaxf(h[(size_t)n * DIM + lane], 0.f);
    }
    atomicAdd(&g[(size_t)curb * DIM + lane], run);
}

// ---------------- head ----------------
__global__ __launch_bounds__(64) void k_head(const float* __restrict__ g,
        const float* __restrict__ W1, const float* __restrict__ b1,
        const float* __restrict__ W2, const float* __restrict__ b2,
        float* __restrict__ out) {
    __shared__ float gs[DIM];
    __shared__ float a1[DIM];
    __shared__ float lg[NC];
    int t = threadIdx.x;
    int gr = blockIdx.x;
    if (t < DIM) gs[t] = g[(size_t)gr * DIM + t];
    __syncthreads();
    if (t < DIM) {
        float a = b1[t];
        #pragma unroll
        for (int k = 0; k < DIM; ++k) a += gs[k] * W1[k * DIM + t];
        a1[t] = fmaxf(a, 0.f);
    }
    __syncthreads();
    if (t < NC) {
        float a = b2[t];
        #pragma unroll
        for (int k = 0; k < DIM; ++k) a += a1[k] * W2[k * NC + t];
        lg[t] = a;
    }
    __syncthreads();
    if (t == 0) {
        float m = lg[0];
        for (int c = 1; c < NC; ++c) m = fmaxf(m, lg[c]);
        float s = 0.f;
        for (int c = 0; c < NC; ++c) s += expf(lg[c] - m);
        float ls = m + logf(s);
        for (int c = 0; c < NC; ++c) out[(size_t)gr * NC + c] = lg[c] - ls;
    }
}

extern "C" void kernel_launch(void* const* d_in, const int* in_sizes, int n_in,
                              void* d_out, int out_size, void* d_ws, size_t ws_size,
                              hipStream_t stream) {
    const float* x     = (const float*)d_in[0];
    const int*   ei    = (const int*)d_in[1];
    const int*   batch = (const int*)d_in[2];
    const float* ew    = (const float*)d_in[3];
    const float* Wrel[5]  = {(const float*)d_in[4],  (const float*)d_in[7],  (const float*)d_in[10], (const float*)d_in[13], (const float*)d_in[16]};
    const float* brel[5]  = {(const float*)d_in[5],  (const float*)d_in[8],  (const float*)d_in[11], (const float*)d_in[14], (const float*)d_in[17]};
    const float* Wroot[5] = {(const float*)d_in[6],  (const float*)d_in[9],  (const float*)d_in[12], (const float*)d_in[15], (const float*)d_in[18]};
    const float* W1 = (const float*)d_in[19];
    const float* b1 = (const float*)d_in[20];
    const float* W2 = (const float*)d_in[21];
    const float* b2 = (const float*)d_in[22];
    float* out = (float*)d_out;

    char* ws = (char*)d_ws;
    const size_t off_cursor = 0;                                   // 512*16*4 = 32768
    const size_t off_g      = 32768;                               // 128000
    const size_t zero_end   = 160768;
    const size_t off_ebuf   = 160768;                              // 16-B aligned
    const size_t off_od     = off_ebuf + ((size_t)NBKT * BCAP + 64) * 8;
    const size_t off_A      = off_od + (size_t)NN * 8;
    const size_t off_B      = off_A + (size_t)NN * DIM * 4;
    const size_t off_C      = off_B + (size_t)NN * DIM * 2;
    const size_t need       = off_C + (size_t)NN * DIM * 4;        // ~50 MB
    if (ws_size < need) return;

    int*    cursor = (int*)(ws + off_cursor);
    float*  g      = (float*)(ws + off_g);
    uint2*  ebuf   = (uint2*)(ws + off_ebuf);
    uint2*  od     = (uint2*)(ws + off_od);
    float*  A      = (float*)(ws + off_A);
    ushort* B      = (ushort*)(ws + off_B);
    float*  C      = (float*)(ws + off_C);

    int zcount = (int)(zero_end / 4);
    k_zero<<<(zcount + 255) / 256, 256, 0, stream>>>((u32*)ws, zcount);

    const int nbin = (NE + RND - 1) / RND;             // 782
    k_bin<<<nbin, 256, 0, stream>>>(ei, ew, cursor, ebuf);
    k_csr<<<NBKT, 256, 0, stream>>>(ebuf, cursor, od);

    const int nmm1 = (NN + 63) / 64;                   // 1563
    const int nmm  = (NN + 127) / 128;                 // 782
    const int ngt  = (NN + 7) / 8;                     // 12500
    k_mm1<<<nmm1, 256, 0, stream>>>(x, Wrel[0], brel[0], Wroot[0], B, A);
    k_gather<<<ngt, 256, 0, stream>>>(B, ebuf, od, A);

    float* cur = A; float* nxt = C;
    for (int L = 1; L < 5; ++L) {
        k_mm_small<<<nmm, 256, 0, stream>>>(cur, Wrel[L], brel[L], Wroot[L], B, nxt);
        k_gather<<<ngt, 256, 0, stream>>>(B, ebuf, od, nxt);
        float* tmp = cur; cur = nxt; nxt = tmp;
    }

    k_pool<<<391, 256, 0, stream>>>(cur, batch, g);
    k_head<<<NG, 64, 0, stream>>>(g, W1, b1, W2, b2, out);
}

// Round 10
// 448.239 us; speedup vs baseline: 1.0865x; 1.0865x over previous
//
#include <hip/hip_runtime.h>
#include <stdint.h>

#define NN 100000
#define NE 1600000
#define NG 1000
#define FIN 128
#define DIM 32
#define NC 10

#define NBKT 512          // super-buckets over dst nodes
#define NPB 196           // nodes per bucket (512*196 = 100352 >= NN)
#define BCAP 4096         // edges per bucket (mean 3136 + <=196 pad, ~10 sigma headroom)
#define RND 2048          // edges per binning block
#define CURS 16           // cursor stride in ints (one per 64-B line)

typedef unsigned int u32;
typedef __attribute__((ext_vector_type(8))) short short8;
typedef __attribute__((ext_vector_type(4))) float floatx4;
typedef __attribute__((ext_vector_type(4))) unsigned int uint4e;   // vector-of-int: nontemporal-builtin legal

__device__ __forceinline__ ushort f2bf(float f) {
    u32 b = __float_as_uint(f);
    return (ushort)((b + 0x7FFFu + ((b >> 16) & 1u)) >> 16);   // RNE
}
__device__ __forceinline__ float bf2f(ushort u) {
    return __uint_as_float(((u32)u) << 16);
}

// ---------------- zero ----------------
__global__ void k_zero(u32* __restrict__ p, int n) {
    int i = blockIdx.x * blockDim.x + threadIdx.x;
    if (i < n) p[i] = 0u;
}

// ---------------- binning: edges -> 512 dst-super-buckets, LDS write-combined ----------------
__global__ __launch_bounds__(256) void k_bin(const int* __restrict__ ei,
        const float* __restrict__ ew, int* __restrict__ cursor,
        uint2* __restrict__ ebuf) {
    __shared__ uint2  ent[RND];
    __shared__ ushort bk16[RND];
    __shared__ int cnt[NBKT];
    __shared__ int sA[NBKT];
    __shared__ int sB[NBKT];
    __shared__ int gbase[NBKT];
    int tid = threadIdx.x;
    int e0 = blockIdx.x * RND;
    int n  = min(RND, NE - e0);
    if (n <= 0) return;

    for (int i = tid; i < NBKT; i += 256) cnt[i] = 0;
    __syncthreads();

    u32 pk[8], wv[8], bp[8];
    #pragma unroll
    for (int q = 0; q < 8; ++q) {
        int i = tid + q * 256;
        pk[q] = 0; wv[q] = 0; bp[q] = 0;
        if (i < n) {
            int s = ei[e0 + i];
            int d = ei[NE + e0 + i];
            float w = ew[e0 + i];
            int b = d / NPB;
            int loc = d - b * NPB;
            int p = atomicAdd(&cnt[b], 1);
            pk[q] = (u32)s | ((u32)loc << 17);
            wv[q] = __float_as_uint(w);
            bp[q] = (u32)p | ((u32)b << 16);
        }
    }
    __syncthreads();

    for (int i = tid; i < NBKT; i += 256) sA[i] = cnt[i];
    __syncthreads();
    int* ssrc = sA; int* sdst = sB;
    for (int dd = 1; dd < NBKT; dd <<= 1) {
        for (int i = tid; i < NBKT; i += 256)
            sdst[i] = ssrc[i] + (i >= dd ? ssrc[i - dd] : 0);
        __syncthreads();
        int* t = ssrc; ssrc = sdst; sdst = t;
    }
    for (int i = tid; i < NBKT; i += 256) {
        int excl = ssrc[i] - cnt[i];
        sdst[i] = excl;
        if (cnt[i] > 0) gbase[i] = atomicAdd(&cursor[i * CURS], cnt[i]);
    }
    __syncthreads();
    int* basep = sdst;

    #pragma unroll
    for (int q = 0; q < 8; ++q) {
        int i = tid + q * 256;
        if (i < n) {
            int b = (int)(bp[q] >> 16);
            int p = (int)(bp[q] & 0xFFFFu);
            int pos = basep[b] + p;
            ent[pos]  = make_uint2(pk[q], wv[q]);
            bk16[pos] = (ushort)b;
        }
    }
    __syncthreads();

    for (int i = tid; i < n; i += 256) {
        int b = (int)bk16[i];
        int dsti = gbase[b] + (i - basep[b]);
        if (dsti < BCAP) ebuf[(size_t)b * BCAP + dsti] = ent[i];
    }
}

// ---------------- CSR: counting-sort each bucket by local node; segments padded to even
//                  (16-B aligned) starts, pads zero-filled; emit (off,deg) ----------------
__global__ __launch_bounds__(256) void k_csr(uint2* __restrict__ ebuf,
        const int* __restrict__ cursor, uint2* __restrict__ od) {
    __shared__ uint2 ent[BCAP];      // 32 KB
    __shared__ int hist[NPB];
    __shared__ int sc[NPB];
    __shared__ int base[NPB];
    int tid = threadIdx.x;
    int bkt = blockIdx.x;
    int cnt = min(cursor[bkt * CURS], BCAP);
    for (int i = tid; i < NPB; i += 256) hist[i] = 0;
    __syncthreads();
    uint2* gb = ebuf + (size_t)bkt * BCAP;
    uint2 my[16]; int mp[16];
    #pragma unroll
    for (int q = 0; q < 16; ++q) {
        int i = tid + q * 256;
        mp[q] = -1;
        if (i < cnt) {
            my[q] = gb[i];
            int loc = (int)(my[q].x >> 17);
            mp[q] = atomicAdd(&hist[loc], 1);
        }
    }
    __syncthreads();
    // inclusive scan of even-padded sizes
    for (int i = tid; i < NPB; i += 256) sc[i] = (hist[i] + 1) & ~1;
    __syncthreads();
    for (int dd = 1; dd < NPB; dd <<= 1) {
        int v = 0;
        if (tid < NPB) { v = sc[tid]; if (tid >= dd) v += sc[tid - dd]; }
        __syncthreads();
        if (tid < NPB) sc[tid] = v;
        __syncthreads();
    }
    for (int i = tid; i < NPB; i += 256) base[i] = sc[i] - ((hist[i] + 1) & ~1);
    __syncthreads();
    int tot = min(sc[NPB - 1], BCAP);
    for (int i = tid; i < tot; i += 256) ent[i] = make_uint2(0u, 0u);  // zero pads
    __syncthreads();
    #pragma unroll
    for (int q = 0; q < 16; ++q) {
        if (mp[q] >= 0) {
            int loc = (int)(my[q].x >> 17);
            int pos = base[loc] + mp[q];
            if (pos < BCAP) ent[pos] = my[q];
        }
    }
    __syncthreads();
    for (int i = tid; i < tot; i += 256) gb[i] = ent[i];
    for (int i = tid; i < NPB; i += 256) {
        int node = bkt * NPB + i;
        if (node < NN) {
            int dg = hist[i];
            if (base[i] + dg > BCAP) dg = max(0, BCAP - base[i]);   // statistically never
            od[node] = make_uint2((u32)(bkt * BCAP + base[i]), (u32)dg);
        }
    }
}

// ---------------- layer-1 matmul via bf16 MFMA ----------------
__global__ __launch_bounds__(256) void k_mm1(const float* __restrict__ x,
        const float* __restrict__ Wrel, const float* __restrict__ brel,
        const float* __restrict__ Wroot,
        ushort* __restrict__ ybf, float* __restrict__ aggi) {
    __shared__ ushort xs[64 * 136];
    int tid = threadIdx.x;
    int base = blockIdx.x * 64;
    for (int i = tid; i < 64 * 32; i += 256) {
        int r = i >> 5, c = i & 31;
        int node = base + r;
        float4 v = make_float4(0.f, 0.f, 0.f, 0.f);
        if (node < NN) v = ((const float4*)x)[(size_t)node * 32 + c];
        ushort4 u;
        u.x = f2bf(v.x); u.y = f2bf(v.y); u.z = f2bf(v.z); u.w = f2bf(v.w);
        *(ushort4*)&xs[r * 136 + c * 4] = u;
    }
    int lane = tid & 63;
    int w = tid >> 6;
    int m = lane & 15;
    int q = lane >> 4;
    short8 bfr[4][4];
    #pragma unroll
    for (int nt = 0; nt < 4; ++nt) {
        const float* W = (nt < 2) ? Wrel : Wroot;
        int ncol = (nt & 1) * 16 + m;
        #pragma unroll
        for (int kc = 0; kc < 4; ++kc) {
            short8 fr;
            #pragma unroll
            for (int j = 0; j < 8; ++j) {
                int k = kc * 32 + q * 8 + j;
                fr[j] = (short)f2bf(W[k * 32 + ncol]);
            }
            bfr[nt][kc] = fr;
        }
    }
    __syncthreads();
    floatx4 acc[4] = {{0.f,0.f,0.f,0.f},{0.f,0.f,0.f,0.f},{0.f,0.f,0.f,0.f},{0.f,0.f,0.f,0.f}};
    #pragma unroll
    for (int kc = 0; kc < 4; ++kc) {
        short8 af = *(const short8*)&xs[(w * 16 + m) * 136 + kc * 32 + q * 8];
        #pragma unroll
        for (int nt = 0; nt < 4; ++nt)
            acc[nt] = __builtin_amdgcn_mfma_f32_16x16x32_bf16(af, bfr[nt][kc], acc[nt], 0, 0, 0);
    }
    float br0 = brel[m], br1 = brel[16 + m];
    #pragma unroll
    for (int reg = 0; reg < 4; ++reg) {
        int row = q * 4 + reg;
        int node = base + w * 16 + row;
        if (node < NN) {
            ybf[(size_t)node * 32 + m]       = f2bf(acc[0][reg]);
            ybf[(size_t)node * 32 + 16 + m]  = f2bf(acc[1][reg]);
            aggi[(size_t)node * 32 + m]      = acc[2][reg] + br0;
            aggi[(size_t)node * 32 + 16 + m] = acc[3][reg] + br1;
        }
    }
}

// ---------------- fused gather + relu + next-layer dual matmul ----------------
// agg_total = aggi_cur + sum_j w_j*y[src_j]; h = relu(agg_total);
// ybf_next = bf16(h @ Wrel); aggi_next = h @ Wroot + brel.
// Grid is exactly NN/8 blocks * 8 nodes -> no divergent exits before __syncthreads.
__global__ __launch_bounds__(256, 6) void k_gfused(const ushort* __restrict__ ybf,
        const uint2* __restrict__ ebuf, const uint2* __restrict__ od,
        const float* __restrict__ aggi,
        const float* __restrict__ Wrel, const float* __restrict__ brel,
        const float* __restrict__ Wroot,
        ushort* __restrict__ ybf_n, float* __restrict__ aggi_n) {
    __shared__ float wr[DIM * DIM];
    __shared__ float wo[DIM * DIM];
    __shared__ float hsm[8][DIM + 1];
    int tid = threadIdx.x;
    for (int i = tid; i < DIM * DIM / 4; i += 256) {
        ((float4*)wr)[i] = ((const float4*)Wrel)[i];
        ((float4*)wo)[i] = ((const float4*)Wroot)[i];
    }
    int f = tid & 31;
    int ng = tid >> 5;
    int node = blockIdx.x * 8 + ng;           // grid*8 == NN exactly
    uint2 o = od[node];
    int deg = (int)o.y;
    const uint4e* eb4 = (const uint4e*)(ebuf + o.x);   // o.x even -> 16-B aligned
    const ushort* yb = ybf + f;
    size_t oo = (size_t)node * DIM + f;
    float prev = __builtin_nontemporal_load(&aggi[oo]);
    float acc0 = 0.f, acc1 = 0.f;
    for (int b = 0; b < deg; b += 16) {
        const uint4e* p = eb4 + (b >> 1);
        uint4e e0 = __builtin_nontemporal_load(p + 0);
        uint4e e1 = __builtin_nontemporal_load(p + 1);
        uint4e e2 = __builtin_nontemporal_load(p + 2);
        uint4e e3 = __builtin_nontemporal_load(p + 3);
        uint4e e4 = __builtin_nontemporal_load(p + 4);
        uint4e e5 = __builtin_nontemporal_load(p + 5);
        uint4e e6 = __builtin_nontemporal_load(p + 6);
        uint4e e7 = __builtin_nontemporal_load(p + 7);
        float y0  = bf2f(yb[(size_t)(e0.x & 0x1FFFFu) * DIM]);
        float y1  = bf2f(yb[(size_t)(e0.z & 0x1FFFFu) * DIM]);
        float y2  = bf2f(yb[(size_t)(e1.x & 0x1FFFFu) * DIM]);
        float y3  = bf2f(yb[(size_t)(e1.z & 0x1FFFFu) * DIM]);
        float y4  = bf2f(yb[(size_t)(e2.x & 0x1FFFFu) * DIM]);
        float y5  = bf2f(yb[(size_t)(e2.z & 0x1FFFFu) * DIM]);
        float y6  = bf2f(yb[(size_t)(e3.x & 0x1FFFFu) * DIM]);
        float y7  = bf2f(yb[(size_t)(e3.z & 0x1FFFFu) * DIM]);
        float y8  = bf2f(yb[(size_t)(e4.x & 0x1FFFFu) * DIM]);
        float y9  = bf2f(yb[(size_t)(e4.z & 0x1FFFFu) * DIM]);
        float y10 = bf2f(yb[(size_t)(e5.x & 0x1FFFFu) * DIM]);
        float y11 = bf2f(yb[(size_t)(e5.z & 0x1FFFFu) * DIM]);
        float y12 = bf2f(yb[(size_t)(e6.x & 0x1FFFFu) * DIM]);
        float y13 = bf2f(yb[(size_t)(e6.z & 0x1FFFFu) * DIM]);
        float y14 = bf2f(yb[(size_t)(e7.x & 0x1FFFFu) * DIM]);
        float y15 = bf2f(yb[(size_t)(e7.z & 0x1FFFFu) * DIM]);
        int r = deg - b;
        acc0 += (( 0 < r) ? __uint_as_float(e0.y) : 0.f) * y0;
        acc1 += (( 1 < r) ? __uint_as_float(e0.w) : 0.f) * y1;
        acc0 += (( 2 < r) ? __uint_as_float(e1.y) : 0.f) * y2;
        acc1 += (( 3 < r) ? __uint_as_float(e1.w) : 0.f) * y3;
        acc0 += (( 4 < r) ? __uint_as_float(e2.y) : 0.f) * y4;
        acc1 += (( 5 < r) ? __uint_as_float(e2.w) : 0.f) * y5;
        acc0 += (( 6 < r) ? __uint_as_float(e3.y) : 0.f) * y6;
        acc1 += (( 7 < r) ? __uint_as_float(e3.w) : 0.f) * y7;
        acc0 += (( 8 < r) ? __uint_as_float(e4.y) : 0.f) * y8;
        acc1 += (( 9 < r) ? __uint_as_float(e4.w) : 0.f) * y9;
        acc0 += ((10 < r) ? __uint_as_float(e5.y) : 0.f) * y10;
        acc1 += ((11 < r) ? __uint_as_float(e5.w) : 0.f) * y11;
        acc0 += ((12 < r) ? __uint_as_float(e6.y) : 0.f) * y12;
        acc1 += ((13 < r) ? __uint_as_float(e6.w) : 0.f) * y13;
        acc0 += ((14 < r) ? __uint_as_float(e7.y) : 0.f) * y14;
        acc1 += ((15 < r) ? __uint_as_float(e7.w) : 0.f) * y15;
    }
    hsm[ng][f] = fmaxf(prev + acc0 + acc1, 0.f);
    __syncthreads();
    // next-layer matmul epilogue: hsm broadcast reads (free), wr/wo consecutive (conflict-free)
    float ya = 0.f, aa = brel[f];
    #pragma unroll
    for (int k = 0; k < DIM; ++k) {
        float hv = hsm[ng][k];
        ya += hv * wr[k * DIM + f];
        aa += hv * wo[k * DIM + f];
    }
    ybf_n[oo] = f2bf(ya);
    __builtin_nontemporal_store(aa, &aggi_n[oo]);
}

// ---------------- last-layer gather: h = relu(aggi + sum) ----------------
__global__ __launch_bounds__(256, 6) void k_glast(const ushort* __restrict__ ybf,
        const uint2* __restrict__ ebuf, const uint2* __restrict__ od,
        const float* __restrict__ aggi, float* __restrict__ h) {
    int tid = threadIdx.x;
    int f = tid & 31;
    int node = blockIdx.x * 8 + (tid >> 5);
    if (node >= NN) return;
    uint2 o = od[node];
    int deg = (int)o.y;
    const uint4e* eb4 = (const uint4e*)(ebuf + o.x);
    const ushort* yb = ybf + f;
    size_t oo = (size_t)node * DIM + f;
    float prev = __builtin_nontemporal_load(&aggi[oo]);
    float acc0 = 0.f, acc1 = 0.f;
    for (int b = 0; b < deg; b += 16) {
        const uint4e* p = eb4 + (b >> 1);
        uint4e e0 = __builtin_nontemporal_load(p + 0);
        uint4e e1 = __builtin_nontemporal_load(p + 1);
        uint4e e2 = __builtin_nontemporal_load(p + 2);
        uint4e e3 = __builtin_nontemporal_load(p + 3);
        uint4e e4 = __builtin_nontemporal_load(p + 4);
        uint4e e5 = __builtin_nontemporal_load(p + 5);
        uint4e e6 = __builtin_nontemporal_load(p + 6);
        uint4e e7 = __builtin_nontemporal_load(p + 7);
        float y0  = bf2f(yb[(size_t)(e0.x & 0x1FFFFu) * DIM]);
        float y1  = bf2f(yb[(size_t)(e0.z & 0x1FFFFu) * DIM]);
        float y2  = bf2f(yb[(size_t)(e1.x & 0x1FFFFu) * DIM]);
        float y3  = bf2f(yb[(size_t)(e1.z & 0x1FFFFu) * DIM]);
        float y4  = bf2f(yb[(size_t)(e2.x & 0x1FFFFu) * DIM]);
        float y5  = bf2f(yb[(size_t)(e2.z & 0x1FFFFu) * DIM]);
        float y6  = bf2f(yb[(size_t)(e3.x & 0x1FFFFu) * DIM]);
        float y7  = bf2f(yb[(size_t)(e3.z & 0x1FFFFu) * DIM]);
        float y8  = bf2f(yb[(size_t)(e4.x & 0x1FFFFu) * DIM]);
        float y9  = bf2f(yb[(size_t)(e4.z & 0x1FFFFu) * DIM]);
        float y10 = bf2f(yb[(size_t)(e5.x & 0x1FFFFu) * DIM]);
        float y11 = bf2f(yb[(size_t)(e5.z & 0x1FFFFu) * DIM]);
        float y12 = bf2f(yb[(size_t)(e6.x & 0x1FFFFu) * DIM]);
        float y13 = bf2f(yb[(size_t)(e6.z & 0x1FFFFu) * DIM]);
        float y14 = bf2f(yb[(size_t)(e7.x & 0x1FFFFu) * DIM]);
        float y15 = bf2f(yb[(size_t)(e7.z & 0x1FFFFu) * DIM]);
        int r = deg - b;
        acc0 += (( 0 < r) ? __uint_as_float(e0.y) : 0.f) * y0;
        acc1 += (( 1 < r) ? __uint_as_float(e0.w) : 0.f) * y1;
        acc0 += (( 2 < r) ? __uint_as_float(e1.y) : 0.f) * y2;
        acc1 += (( 3 < r) ? __uint_as_float(e1.w) : 0.f) * y3;
        acc0 += (( 4 < r) ? __uint_as_float(e2.y) : 0.f) * y4;
        acc1 += (( 5 < r) ? __uint_as_float(e2.w) : 0.f) * y5;
        acc0 += (( 6 < r) ? __uint_as_float(e3.y) : 0.f) * y6;
        acc1 += (( 7 < r) ? __uint_as_float(e3.w) : 0.f) * y7;
        acc0 += (( 8 < r) ? __uint_as_float(e4.y) : 0.f) * y8;
        acc1 += (( 9 < r) ? __uint_as_float(e4.w) : 0.f) * y9;
        acc0 += ((10 < r) ? __uint_as_float(e5.y) : 0.f) * y10;
        acc1 += ((11 < r) ? __uint_as_float(e5.w) : 0.f) * y11;
        acc0 += ((12 < r) ? __uint_as_float(e6.y) : 0.f) * y12;
        acc1 += ((13 < r) ? __uint_as_float(e6.w) : 0.f) * y13;
        acc0 += ((14 < r) ? __uint_as_float(e7.y) : 0.f) * y14;
        acc1 += ((15 < r) ? __uint_as_float(e7.w) : 0.f) * y15;
    }
    __builtin_nontemporal_store(fmaxf(prev + acc0 + acc1, 0.f), &h[oo]);
}

// ---------------- pool: g[batch[n]] += h[n]; batch sorted ----------------
#define STRIP 32
__global__ __launch_bounds__(256) void k_pool(const float* __restrict__ h,
        const int* __restrict__ batch, float* __restrict__ g) {
    int tid = threadIdx.x;
    int lane = tid & 31;
    int grp = blockIdx.x * 8 + (tid >> 5);
    int start = grp * STRIP;
    if (start >= NN) return;
    int end = min(start + STRIP, NN);
    int curb = batch[start];
    float run = 0.f;
    for (int n = start; n < end; ++n) {
        int b = batch[n];
        if (b != curb) {
            atomicAdd(&g[(size_t)curb * DIM + lane], run);
            run = 0.f; curb = b;
        }
        run += h[(size_t)n * DIM + lane];        // h already relu'd
    }
    atomicAdd(&g[(size_t)curb * DIM + lane], run);
}

// ---------------- head ----------------
__global__ __launch_bounds__(64) void k_head(const float* __restrict__ g,
        const float* __restrict__ W1, const float* __restrict__ b1,
        const float* __restrict__ W2, const float* __restrict__ b2,
        float* __restrict__ out) {
    __shared__ float gs[DIM];
    __shared__ float a1[DIM];
    __shared__ float lg[NC];
    int t = threadIdx.x;
    int gr = blockIdx.x;
    if (t < DIM) gs[t] = g[(size_t)gr * DIM + t];
    __syncthreads();
    if (t < DIM) {
        float a = b1[t];
        #pragma unroll
        for (int k = 0; k < DIM; ++k) a += gs[k] * W1[k * DIM + t];
        a1[t] = fmaxf(a, 0.f);
    }
    __syncthreads();
    if (t < NC) {
        float a = b2[t];
        #pragma unroll
        for (int k = 0; k < DIM; ++k) a += a1[k] * W2[k * NC + t];
        lg[t] = a;
    }
    __syncthreads();
    if (t == 0) {
        float m = lg[0];
        for (int c = 1; c < NC; ++c) m = fmaxf(m, lg[c]);
        float s = 0.f;
        for (int c = 0; c < NC; ++c) s += expf(lg[c] - m);
        float ls = m + logf(s);
        for (int c = 0; c < NC; ++c) out[(size_t)gr * NC + c] = lg[c] - ls;
    }
}

extern "C" void kernel_launch(void* const* d_in, const int* in_sizes, int n_in,
                              void* d_out, int out_size, void* d_ws, size_t ws_size,
                              hipStream_t stream) {
    const float* x     = (const float*)d_in[0];
    const int*   ei    = (const int*)d_in[1];
    const int*   batch = (const int*)d_in[2];
    const float* ew    = (const float*)d_in[3];
    const float* Wrel[5]  = {(const float*)d_in[4],  (const float*)d_in[7],  (const float*)d_in[10], (const float*)d_in[13], (const float*)d_in[16]};
    const float* brel[5]  = {(const float*)d_in[5],  (const float*)d_in[8],  (const float*)d_in[11], (const float*)d_in[14], (const float*)d_in[17]};
    const float* Wroot[5] = {(const float*)d_in[6],  (const float*)d_in[9],  (const float*)d_in[12], (const float*)d_in[15], (const float*)d_in[18]};
    const float* W1 = (const float*)d_in[19];
    const float* b1 = (const float*)d_in[20];
    const float* W2 = (const float*)d_in[21];
    const float* b2 = (const float*)d_in[22];
    float* out = (float*)d_out;

    char* ws = (char*)d_ws;
    const size_t off_cursor = 0;                                   // 512*16*4 = 32768
    const size_t off_g      = 32768;                               // 128000
    const size_t zero_end   = 160768;
    const size_t off_ebuf   = 160768;                              // 16-B aligned
    const size_t off_od     = off_ebuf + ((size_t)NBKT * BCAP + 64) * 8;
    const size_t off_A     = off_od + (size_t)NN * 8;              // aggi ping
    const size_t off_C     = off_A + (size_t)NN * DIM * 4;         // aggi pong / h
    const size_t off_B1    = off_C + (size_t)NN * DIM * 4;         // y ping (bf16)
    const size_t off_B2    = off_B1 + (size_t)NN * DIM * 2;        // y pong (bf16)
    const size_t need      = off_B2 + (size_t)NN * DIM * 2;        // ~56 MB
    if (ws_size < need) return;

    int*    cursor = (int*)(ws + off_cursor);
    float*  g      = (float*)(ws + off_g);
    uint2*  ebuf   = (uint2*)(ws + off_ebuf);
    uint2*  od     = (uint2*)(ws + off_od);
    float*  A      = (float*)(ws + off_A);
    float*  C      = (float*)(ws + off_C);
    ushort* B1     = (ushort*)(ws + off_B1);
    ushort* B2     = (ushort*)(ws + off_B2);

    int zcount = (int)(zero_end / 4);
    k_zero<<<(zcount + 255) / 256, 256, 0, stream>>>((u32*)ws, zcount);

    const int nbin = (NE + RND - 1) / RND;             // 782
    k_bin<<<nbin, 256, 0, stream>>>(ei, ew, cursor, ebuf);
    k_csr<<<NBKT, 256, 0, stream>>>(ebuf, cursor, od);

    const int nmm1 = (NN + 63) / 64;                   // 1563
    const int ngt  = NN / 8;                           // 12500 (exact)
    k_mm1<<<nmm1, 256, 0, stream>>>(x, Wrel[0], brel[0], Wroot[0], B1, A);

    float*  aggc = A;  float*  aggn = C;
    ushort* yc   = B1; ushort* yn   = B2;
    for (int L = 1; L < 5; ++L) {
        k_gfused<<<ngt, 256, 0, stream>>>(yc, ebuf, od, aggc,
                                          Wrel[L], brel[L], Wroot[L], yn, aggn);
        float* tf = aggc; aggc = aggn; aggn = tf;
        ushort* tu = yc; yc = yn; yn = tu;
    }
    // final layer: h = relu(aggc + gather(yc)) -> aggn buffer
    k_glast<<<ngt, 256, 0, stream>>>(yc, ebuf, od, aggc, aggn);

    k_pool<<<391, 256, 0, stream>>>(aggn, batch, g);
    k_head<<<NG, 64, 0, stream>>>(g, W1, b1, W2, b2, out);
}

// Round 11
// 431.540 us; speedup vs baseline: 1.1286x; 1.0387x over previous
//
#include <hip/hip_runtime.h>
#include <stdint.h>

#define NN 100000
#define NE 1600000
#define NG 1000
#define FIN 128
#define DIM 32
#define NC 10

#define NBKT 512          // super-buckets over dst nodes
#define NPB 196           // nodes per bucket (512*196 = 100352 >= NN)
#define BCAP 4096         // edges per bucket (mean 3136 + <=196 pad, ~10 sigma headroom)
#define RND 2048          // edges per binning block
#define CURS 16           // cursor stride in ints (one per 64-B line)
#define NBINB 782         // binning blocks
#define NMM1 1563         // mm1 blocks (64 nodes each)
#define MM1P1 781         // mm1 blocks co-dispatched with bin
#define MM1P2 782         // mm1 blocks co-dispatched with csr

typedef unsigned int u32;
typedef __attribute__((ext_vector_type(8))) short short8;
typedef __attribute__((ext_vector_type(4))) float floatx4;
typedef __attribute__((ext_vector_type(4))) unsigned int uint4e;

__device__ __forceinline__ ushort f2bf(float f) {
    u32 b = __float_as_uint(f);
    return (ushort)((b + 0x7FFFu + ((b >> 16) & 1u)) >> 16);   // RNE
}
__device__ __forceinline__ float bf2f(ushort u) {
    return __uint_as_float(((u32)u) << 16);
}

// shared-memory union for the combined dispatches
union SMemU {
    struct {               // binning
        uint2  ent[RND];
        ushort bk16[RND];
        int cnt[NBKT]; int sA[NBKT]; int sB[NBKT]; int gbase[NBKT];
    } b;                   // 28.0 KB
    struct {               // csr
        uint2 ent[BCAP];
        int hist[NPB]; int sc[NPB]; int base[NPB];
    } c;                   // 34.4 KB
    struct {               // mm1
        ushort xs[64 * 136];
        float wrel[FIN * DIM];
        float wroot[FIN * DIM];
    } m;                   // 49.0 KB
};

// ---------------- zero ----------------
__global__ void k_zero(u32* __restrict__ p, int n) {
    int i = blockIdx.x * blockDim.x + threadIdx.x;
    if (i < n) p[i] = 0u;
}

// ---------------- bodies ----------------
__device__ void bin_body(SMemU& sm, int blk, const int* __restrict__ ei,
        const float* __restrict__ ew, int* __restrict__ cursor,
        uint2* __restrict__ ebuf) {
    int tid = threadIdx.x;
    int e0 = blk * RND;
    int n  = min(RND, NE - e0);

    for (int i = tid; i < NBKT; i += 256) sm.b.cnt[i] = 0;
    __syncthreads();

    u32 pk[8], wv[8], bp[8];
    #pragma unroll
    for (int q = 0; q < 8; ++q) {
        int i = tid + q * 256;
        pk[q] = 0; wv[q] = 0; bp[q] = 0;
        if (i < n) {
            int s = ei[e0 + i];
            int d = ei[NE + e0 + i];
            float w = ew[e0 + i];
            int b = d / NPB;
            int loc = d - b * NPB;
            int p = atomicAdd(&sm.b.cnt[b], 1);
            pk[q] = (u32)s | ((u32)loc << 17);
            wv[q] = __float_as_uint(w);
            bp[q] = (u32)p | ((u32)b << 16);
        }
    }
    __syncthreads();

    for (int i = tid; i < NBKT; i += 256) sm.b.sA[i] = sm.b.cnt[i];
    __syncthreads();
    int* ssrc = sm.b.sA; int* sdst = sm.b.sB;
    for (int dd = 1; dd < NBKT; dd <<= 1) {
        for (int i = tid; i < NBKT; i += 256)
            sdst[i] = ssrc[i] + (i >= dd ? ssrc[i - dd] : 0);
        __syncthreads();
        int* t = ssrc; ssrc = sdst; sdst = t;
    }
    for (int i = tid; i < NBKT; i += 256) {
        int excl = ssrc[i] - sm.b.cnt[i];
        sdst[i] = excl;
        if (sm.b.cnt[i] > 0) sm.b.gbase[i] = atomicAdd(&cursor[i * CURS], sm.b.cnt[i]);
    }
    __syncthreads();
    int* basep = sdst;

    #pragma unroll
    for (int q = 0; q < 8; ++q) {
        int i = tid + q * 256;
        if (i < n) {
            int b = (int)(bp[q] >> 16);
            int p = (int)(bp[q] & 0xFFFFu);
            int pos = basep[b] + p;
            sm.b.ent[pos]  = make_uint2(pk[q], wv[q]);
            sm.b.bk16[pos] = (ushort)b;
        }
    }
    __syncthreads();

    for (int i = tid; i < n; i += 256) {
        int b = (int)sm.b.bk16[i];
        int dsti = sm.b.gbase[b] + (i - basep[b]);
        if (dsti < BCAP) ebuf[(size_t)b * BCAP + dsti] = sm.b.ent[i];
    }
}

__device__ void csr_body(SMemU& sm, int bkt, uint2* __restrict__ ebuf,
        const int* __restrict__ cursor, uint2* __restrict__ od) {
    int tid = threadIdx.x;
    int cnt = min(cursor[bkt * CURS], BCAP);
    for (int i = tid; i < NPB; i += 256) sm.c.hist[i] = 0;
    __syncthreads();
    uint2* gb = ebuf + (size_t)bkt * BCAP;
    uint2 my[16]; int mp[16];
    #pragma unroll
    for (int q = 0; q < 16; ++q) {
        int i = tid + q * 256;
        mp[q] = -1;
        if (i < cnt) {
            my[q] = gb[i];
            int loc = (int)(my[q].x >> 17);
            mp[q] = atomicAdd(&sm.c.hist[loc], 1);
        }
    }
    __syncthreads();
    for (int i = tid; i < NPB; i += 256) sm.c.sc[i] = (sm.c.hist[i] + 1) & ~1;
    __syncthreads();
    for (int dd = 1; dd < NPB; dd <<= 1) {
        int v = 0;
        if (tid < NPB) { v = sm.c.sc[tid]; if (tid >= dd) v += sm.c.sc[tid - dd]; }
        __syncthreads();
        if (tid < NPB) sm.c.sc[tid] = v;
        __syncthreads();
    }
    for (int i = tid; i < NPB; i += 256) sm.c.base[i] = sm.c.sc[i] - ((sm.c.hist[i] + 1) & ~1);
    __syncthreads();
    int tot = min(sm.c.sc[NPB - 1], BCAP);
    for (int i = tid; i < tot; i += 256) sm.c.ent[i] = make_uint2(0u, 0u);
    __syncthreads();
    #pragma unroll
    for (int q = 0; q < 16; ++q) {
        if (mp[q] >= 0) {
            int loc = (int)(my[q].x >> 17);
            int pos = sm.c.base[loc] + mp[q];
            if (pos < BCAP) sm.c.ent[pos] = my[q];
        }
    }
    __syncthreads();
    for (int i = tid; i < tot; i += 256) gb[i] = sm.c.ent[i];
    for (int i = tid; i < NPB; i += 256) {
        int node = bkt * NPB + i;
        if (node < NN) {
            int dg = sm.c.hist[i];
            if (sm.c.base[i] + dg > BCAP) dg = max(0, BCAP - sm.c.base[i]);
            od[node] = make_uint2((u32)(bkt * BCAP + sm.c.base[i]), (u32)dg);
        }
    }
}

__device__ void mm1_body(SMemU& sm, int blk, const float* __restrict__ x,
        const float* __restrict__ Wrel, const float* __restrict__ brel,
        const float* __restrict__ Wroot,
        ushort* __restrict__ ybf, float* __restrict__ aggi) {
    int tid = threadIdx.x;
    int base = blk * 64;
    // stage W (coalesced float4) and x (bf16) into LDS
    for (int i = tid; i < FIN * DIM / 4; i += 256) {
        ((float4*)sm.m.wrel)[i]  = ((const float4*)Wrel)[i];
        ((float4*)sm.m.wroot)[i] = ((const float4*)Wroot)[i];
    }
    for (int i = tid; i < 64 * 32; i += 256) {
        int r = i >> 5, c = i & 31;
        int node = base + r;
        float4 v = make_float4(0.f, 0.f, 0.f, 0.f);
        if (node < NN) v = ((const float4*)x)[(size_t)node * 32 + c];
        ushort4 u;
        u.x = f2bf(v.x); u.y = f2bf(v.y); u.z = f2bf(v.z); u.w = f2bf(v.w);
        *(ushort4*)&sm.m.xs[r * 136 + c * 4] = u;
    }
    __syncthreads();
    int lane = tid & 63;
    int w = tid >> 6;
    int m = lane & 15;
    int q = lane >> 4;
    short8 bfr[4][4];
    #pragma unroll
    for (int nt = 0; nt < 4; ++nt) {
        const float* W = (nt < 2) ? sm.m.wrel : sm.m.wroot;
        int ncol = (nt & 1) * 16 + m;
        #pragma unroll
        for (int kc = 0; kc < 4; ++kc) {
            short8 fr;
            #pragma unroll
            for (int j = 0; j < 8; ++j)
                fr[j] = (short)f2bf(W[(kc * 32 + q * 8 + j) * 32 + ncol]);
            bfr[nt][kc] = fr;
        }
    }
    floatx4 acc[4] = {{0.f,0.f,0.f,0.f},{0.f,0.f,0.f,0.f},{0.f,0.f,0.f,0.f},{0.f,0.f,0.f,0.f}};
    #pragma unroll
    for (int kc = 0; kc < 4; ++kc) {
        short8 af = *(const short8*)&sm.m.xs[(w * 16 + m) * 136 + kc * 32 + q * 8];
        #pragma unroll
        for (int nt = 0; nt < 4; ++nt)
            acc[nt] = __builtin_amdgcn_mfma_f32_16x16x32_bf16(af, bfr[nt][kc], acc[nt], 0, 0, 0);
    }
    float br0 = brel[m], br1 = brel[16 + m];
    #pragma unroll
    for (int reg = 0; reg < 4; ++reg) {
        int row = q * 4 + reg;
        int node = base + w * 16 + row;
        if (node < NN) {
            ybf[(size_t)node * 32 + m]       = f2bf(acc[0][reg]);
            ybf[(size_t)node * 32 + 16 + m]  = f2bf(acc[1][reg]);
            aggi[(size_t)node * 32 + m]      = acc[2][reg] + br0;
            aggi[(size_t)node * 32 + 16 + m] = acc[3][reg] + br1;
        }
    }
}

// ---------------- combined dispatches: bin || mm1-half1, csr || mm1-half2 ----------------
__global__ __launch_bounds__(256) void k_pre1(const int* __restrict__ ei,
        const float* __restrict__ ew, int* __restrict__ cursor, uint2* __restrict__ ebuf,
        const float* __restrict__ x, const float* __restrict__ Wrel,
        const float* __restrict__ brel, const float* __restrict__ Wroot,
        ushort* __restrict__ ybf, float* __restrict__ aggi) {
    __shared__ SMemU sm;
    if (blockIdx.x < NBINB) bin_body(sm, blockIdx.x, ei, ew, cursor, ebuf);
    else                    mm1_body(sm, blockIdx.x - NBINB, x, Wrel, brel, Wroot, ybf, aggi);
}

__global__ __launch_bounds__(256) void k_pre2(uint2* __restrict__ ebuf,
        const int* __restrict__ cursor, uint2* __restrict__ od,
        const float* __restrict__ x, const float* __restrict__ Wrel,
        const float* __restrict__ brel, const float* __restrict__ Wroot,
        ushort* __restrict__ ybf, float* __restrict__ aggi) {
    __shared__ SMemU sm;
    if (blockIdx.x < NBKT) csr_body(sm, blockIdx.x, ebuf, cursor, od);
    else                   mm1_body(sm, blockIdx.x - NBKT + MM1P1, x, Wrel, brel, Wroot, ybf, aggi);
}

// ---------------- fused gather + relu + next-layer dual matmul ----------------
__global__ __launch_bounds__(256, 6) void k_gfused(const ushort* __restrict__ ybf,
        const uint2* __restrict__ ebuf, const uint2* __restrict__ od,
        const float* __restrict__ aggi,
        const float* __restrict__ Wrel, const float* __restrict__ brel,
        const float* __restrict__ Wroot,
        ushort* __restrict__ ybf_n, float* __restrict__ aggi_n) {
    __shared__ float wr[DIM * DIM];
    __shared__ float wo[DIM * DIM];
    __shared__ float hsm[8][DIM + 1];
    int tid = threadIdx.x;
    for (int i = tid; i < DIM * DIM / 4; i += 256) {
        ((float4*)wr)[i] = ((const float4*)Wrel)[i];
        ((float4*)wo)[i] = ((const float4*)Wroot)[i];
    }
    int f = tid & 31;
    int ng = tid >> 5;
    int node = blockIdx.x * 8 + ng;           // grid*8 == NN exactly
    uint2 o = od[node];
    int deg = (int)o.y;
    const uint4e* eb4 = (const uint4e*)(ebuf + o.x);
    const ushort* yb = ybf + f;
    size_t oo = (size_t)node * DIM + f;
    float prev = __builtin_nontemporal_load(&aggi[oo]);
    float acc0 = 0.f, acc1 = 0.f;
    for (int b = 0; b < deg; b += 16) {
        const uint4e* p = eb4 + (b >> 1);
        uint4e e0 = __builtin_nontemporal_load(p + 0);
        uint4e e1 = __builtin_nontemporal_load(p + 1);
        uint4e e2 = __builtin_nontemporal_load(p + 2);
        uint4e e3 = __builtin_nontemporal_load(p + 3);
        uint4e e4 = __builtin_nontemporal_load(p + 4);
        uint4e e5 = __builtin_nontemporal_load(p + 5);
        uint4e e6 = __builtin_nontemporal_load(p + 6);
        uint4e e7 = __builtin_nontemporal_load(p + 7);
        float y0  = bf2f(yb[(size_t)(e0.x & 0x1FFFFu) * DIM]);
        float y1  = bf2f(yb[(size_t)(e0.z & 0x1FFFFu) * DIM]);
        float y2  = bf2f(yb[(size_t)(e1.x & 0x1FFFFu) * DIM]);
        float y3  = bf2f(yb[(size_t)(e1.z & 0x1FFFFu) * DIM]);
        float y4  = bf2f(yb[(size_t)(e2.x & 0x1FFFFu) * DIM]);
        float y5  = bf2f(yb[(size_t)(e2.z & 0x1FFFFu) * DIM]);
        float y6  = bf2f(yb[(size_t)(e3.x & 0x1FFFFu) * DIM]);
        float y7  = bf2f(yb[(size_t)(e3.z & 0x1FFFFu) * DIM]);
        float y8  = bf2f(yb[(size_t)(e4.x & 0x1FFFFu) * DIM]);
        float y9  = bf2f(yb[(size_t)(e4.z & 0x1FFFFu) * DIM]);
        float y10 = bf2f(yb[(size_t)(e5.x & 0x1FFFFu) * DIM]);
        float y11 = bf2f(yb[(size_t)(e5.z & 0x1FFFFu) * DIM]);
        float y12 = bf2f(yb[(size_t)(e6.x & 0x1FFFFu) * DIM]);
        float y13 = bf2f(yb[(size_t)(e6.z & 0x1FFFFu) * DIM]);
        float y14 = bf2f(yb[(size_t)(e7.x & 0x1FFFFu) * DIM]);
        float y15 = bf2f(yb[(size_t)(e7.z & 0x1FFFFu) * DIM]);
        int r = deg - b;
        acc0 += (( 0 < r) ? __uint_as_float(e0.y) : 0.f) * y0;
        acc1 += (( 1 < r) ? __uint_as_float(e0.w) : 0.f) * y1;
        acc0 += (( 2 < r) ? __uint_as_float(e1.y) : 0.f) * y2;
        acc1 += (( 3 < r) ? __uint_as_float(e1.w) : 0.f) * y3;
        acc0 += (( 4 < r) ? __uint_as_float(e2.y) : 0.f) * y4;
        acc1 += (( 5 < r) ? __uint_as_float(e2.w) : 0.f) * y5;
        acc0 += (( 6 < r) ? __uint_as_float(e3.y) : 0.f) * y6;
        acc1 += (( 7 < r) ? __uint_as_float(e3.w) : 0.f) * y7;
        acc0 += (( 8 < r) ? __uint_as_float(e4.y) : 0.f) * y8;
        acc1 += (( 9 < r) ? __uint_as_float(e4.w) : 0.f) * y9;
        acc0 += ((10 < r) ? __uint_as_float(e5.y) : 0.f) * y10;
        acc1 += ((11 < r) ? __uint_as_float(e5.w) : 0.f) * y11;
        acc0 += ((12 < r) ? __uint_as_float(e6.y) : 0.f) * y12;
        acc1 += ((13 < r) ? __uint_as_float(e6.w) : 0.f) * y13;
        acc0 += ((14 < r) ? __uint_as_float(e7.y) : 0.f) * y14;
        acc1 += ((15 < r) ? __uint_as_float(e7.w) : 0.f) * y15;
    }
    hsm[ng][f] = fmaxf(prev + acc0 + acc1, 0.f);
    __syncthreads();
    float ya = 0.f, aa = brel[f];
    #pragma unroll
    for (int k = 0; k < DIM; ++k) {
        float hv = hsm[ng][k];
        ya += hv * wr[k * DIM + f];
        aa += hv * wo[k * DIM + f];
    }
    ybf_n[oo] = f2bf(ya);
    __builtin_nontemporal_store(aa, &aggi_n[oo]);
}

// ---------------- fused last gather + relu + pool ----------------
__global__ __launch_bounds__(256, 6) void k_glast_pool(const ushort* __restrict__ ybf,
        const uint2* __restrict__ ebuf, const uint2* __restrict__ od,
        const float* __restrict__ aggi, const int* __restrict__ batch,
        float* __restrict__ g) {
    __shared__ float hsm[8][DIM + 1];
    int tid = threadIdx.x;
    int f = tid & 31;
    int ng = tid >> 5;
    int node = blockIdx.x * 8 + ng;           // grid*8 == NN exactly
    uint2 o = od[node];
    int deg = (int)o.y;
    const uint4e* eb4 = (const uint4e*)(ebuf + o.x);
    const ushort* yb = ybf + f;
    size_t oo = (size_t)node * DIM + f;
    float prev = __builtin_nontemporal_load(&aggi[oo]);
    float acc0 = 0.f, acc1 = 0.f;
    for (int b = 0; b < deg; b += 16) {
        const uint4e* p = eb4 + (b >> 1);
        uint4e e0 = __builtin_nontemporal_load(p + 0);
        uint4e e1 = __builtin_nontemporal_load(p + 1);
        uint4e e2 = __builtin_nontemporal_load(p + 2);
        uint4e e3 = __builtin_nontemporal_load(p + 3);
        uint4e e4 = __builtin_nontemporal_load(p + 4);
        uint4e e5 = __builtin_nontemporal_load(p + 5);
        uint4e e6 = __builtin_nontemporal_load(p + 6);
        uint4e e7 = __builtin_nontemporal_load(p + 7);
        float y0  = bf2f(yb[(size_t)(e0.x & 0x1FFFFu) * DIM]);
        float y1  = bf2f(yb[(size_t)(e0.z & 0x1FFFFu) * DIM]);
        float y2  = bf2f(yb[(size_t)(e1.x & 0x1FFFFu) * DIM]);
        float y3  = bf2f(yb[(size_t)(e1.z & 0x1FFFFu) * DIM]);
        float y4  = bf2f(yb[(size_t)(e2.x & 0x1FFFFu) * DIM]);
        float y5  = bf2f(yb[(size_t)(e2.z & 0x1FFFFu) * DIM]);
        float y6  = bf2f(yb[(size_t)(e3.x & 0x1FFFFu) * DIM]);
        float y7  = bf2f(yb[(size_t)(e3.z & 0x1FFFFu) * DIM]);
        float y8  = bf2f(yb[(size_t)(e4.x & 0x1FFFFu) * DIM]);
        float y9  = bf2f(yb[(size_t)(e4.z & 0x1FFFFu) * DIM]);
        float y10 = bf2f(yb[(size_t)(e5.x & 0x1FFFFu) * DIM]);
        float y11 = bf2f(yb[(size_t)(e5.z & 0x1FFFFu) * DIM]);
        float y12 = bf2f(yb[(size_t)(e6.x & 0x1FFFFu) * DIM]);
        float y13 = bf2f(yb[(size_t)(e6.z & 0x1FFFFu) * DIM]);
        float y14 = bf2f(yb[(size_t)(e7.x & 0x1FFFFu) * DIM]);
        float y15 = bf2f(yb[(size_t)(e7.z & 0x1FFFFu) * DIM]);
        int r = deg - b;
        acc0 += (( 0 < r) ? __uint_as_float(e0.y) : 0.f) * y0;
        acc1 += (( 1 < r) ? __uint_as_float(e0.w) : 0.f) * y1;
        acc0 += (( 2 < r) ? __uint_as_float(e1.y) : 0.f) * y2;
        acc1 += (( 3 < r) ? __uint_as_float(e1.w) : 0.f) * y3;
        acc0 += (( 4 < r) ? __uint_as_float(e2.y) : 0.f) * y4;
        acc1 += (( 5 < r) ? __uint_as_float(e2.w) : 0.f) * y5;
        acc0 += (( 6 < r) ? __uint_as_float(e3.y) : 0.f) * y6;
        acc1 += (( 7 < r) ? __uint_as_float(e3.w) : 0.f) * y7;
        acc0 += (( 8 < r) ? __uint_as_float(e4.y) : 0.f) * y8;
        acc1 += (( 9 < r) ? __uint_as_float(e4.w) : 0.f) * y9;
        acc0 += ((10 < r) ? __uint_as_float(e5.y) : 0.f) * y10;
        acc1 += ((11 < r) ? __uint_as_float(e5.w) : 0.f) * y11;
        acc0 += ((12 < r) ? __uint_as_float(e6.y) : 0.f) * y12;
        acc1 += ((13 < r) ? __uint_as_float(e6.w) : 0.f) * y13;
        acc0 += ((14 < r) ? __uint_as_float(e7.y) : 0.f) * y14;
        acc1 += ((15 < r) ? __uint_as_float(e7.w) : 0.f) * y15;
    }
    hsm[ng][f] = fmaxf(prev + acc0 + acc1, 0.f);
    __syncthreads();
    if (tid < 32) {                            // segmented sum over 8 sorted nodes
        int nb = blockIdx.x * 8;
        int curb = batch[nb];
        float run = 0.f;
        #pragma unroll
        for (int n = 0; n < 8; ++n) {
            int b = batch[nb + n];
            if (b != curb) {
                atomicAdd(&g[(size_t)curb * DIM + tid], run);
                run = 0.f; curb = b;
            }
            run += hsm[n][tid];
        }
        atomicAdd(&g[(size_t)curb * DIM + tid], run);
    }
}

// ---------------- head ----------------
__global__ __launch_bounds__(64) void k_head(const float* __restrict__ g,
        const float* __restrict__ W1, const float* __restrict__ b1,
        const float* __restrict__ W2, const float* __restrict__ b2,
        float* __restrict__ out) {
    __shared__ float gs[DIM];
    __shared__ float a1[DIM];
    __shared__ float lg[NC];
    int t = threadIdx.x;
    int gr = blockIdx.x;
    if (t < DIM) gs[t] = g[(size_t)gr * DIM + t];
    __syncthreads();
    if (t < DIM) {
        float a = b1[t];
        #pragma unroll
        for (int k = 0; k < DIM; ++k) a += gs[k] * W1[k * DIM + t];
        a1[t] = fmaxf(a, 0.f);
    }
    __syncthreads();
    if (t < NC) {
        float a = b2[t];
        #pragma unroll
        for (int k = 0; k < DIM; ++k) a += a1[k] * W2[k * NC + t];
        lg[t] = a;
    }
    __syncthreads();
    if (t == 0) {
        float m = lg[0];
        for (int c = 1; c < NC; ++c) m = fmaxf(m, lg[c]);
        float s = 0.f;
        for (int c = 0; c < NC; ++c) s += expf(lg[c] - m);
        float ls = m + logf(s);
        for (int c = 0; c < NC; ++c) out[(size_t)gr * NC + c] = lg[c] - ls;
    }
}

extern "C" void kernel_launch(void* const* d_in, const int* in_sizes, int n_in,
                              void* d_out, int out_size, void* d_ws, size_t ws_size,
                              hipStream_t stream) {
    const float* x     = (const float*)d_in[0];
    const int*   ei    = (const int*)d_in[1];
    const int*   batch = (const int*)d_in[2];
    const float* ew    = (const float*)d_in[3];
    const float* Wrel[5]  = {(const float*)d_in[4],  (const float*)d_in[7],  (const float*)d_in[10], (const float*)d_in[13], (const float*)d_in[16]};
    const float* brel[5]  = {(const float*)d_in[5],  (const float*)d_in[8],  (const float*)d_in[11], (const float*)d_in[14], (const float*)d_in[17]};
    const float* Wroot[5] = {(const float*)d_in[6],  (const float*)d_in[9],  (const float*)d_in[12], (const float*)d_in[15], (const float*)d_in[18]};
    const float* W1 = (const float*)d_in[19];
    const float* b1 = (const float*)d_in[20];
    const float* W2 = (const float*)d_in[21];
    const float* b2 = (const float*)d_in[22];
    float* out = (float*)d_out;

    char* ws = (char*)d_ws;
    const size_t off_cursor = 0;                                   // 32768
    const size_t off_g      = 32768;                               // 128000
    const size_t zero_end   = 160768;
    const size_t off_ebuf   = 160768;
    const size_t off_od     = off_ebuf + ((size_t)NBKT * BCAP + 64) * 8;
    const size_t off_A      = off_od + (size_t)NN * 8;             // aggi ping
    const size_t off_C      = off_A + (size_t)NN * DIM * 4;        // aggi pong
    const size_t off_B1     = off_C + (size_t)NN * DIM * 4;        // y ping (bf16)
    const size_t off_B2     = off_B1 + (size_t)NN * DIM * 2;       // y pong (bf16)
    const size_t need       = off_B2 + (size_t)NN * DIM * 2;       // ~56 MB
    if (ws_size < need) return;

    int*    cursor = (int*)(ws + off_cursor);
    float*  g      = (float*)(ws + off_g);
    uint2*  ebuf   = (uint2*)(ws + off_ebuf);
    uint2*  od     = (uint2*)(ws + off_od);
    float*  A      = (float*)(ws + off_A);
    float*  C      = (float*)(ws + off_C);
    ushort* B1     = (ushort*)(ws + off_B1);
    ushort* B2     = (ushort*)(ws + off_B2);

    int zcount = (int)(zero_end / 4);
    k_zero<<<(zcount + 255) / 256, 256, 0, stream>>>((u32*)ws, zcount);

    // combined: binning || mm1 first half, then csr || mm1 second half
    k_pre1<<<NBINB + MM1P1, 256, 0, stream>>>(ei, ew, cursor, ebuf,
                                              x, Wrel[0], brel[0], Wroot[0], B1, A);
    k_pre2<<<NBKT + MM1P2, 256, 0, stream>>>(ebuf, cursor, od,
                                             x, Wrel[0], brel[0], Wroot[0], B1, A);

    const int ngt = NN / 8;                    // 12500 (exact)
    float*  aggc = A;  float*  aggn = C;
    ushort* yc   = B1; ushort* yn   = B2;
    for (int L = 1; L < 5; ++L) {
        k_gfused<<<ngt, 256, 0, stream>>>(yc, ebuf, od, aggc,
                                          Wrel[L], brel[L], Wroot[L], yn, aggn);
        float* tf = aggc; aggc = aggn; aggn = tf;
        ushort* tu = yc; yc = yn; yn = tu;
    }
    k_glast_pool<<<ngt, 256, 0, stream>>>(yc, ebuf, od, aggc, batch, g);
    k_head<<<NG, 64, 0, stream>>>(g, W1, b1, W2, b2, out);
}

// Round 12
// 429.384 us; speedup vs baseline: 1.1342x; 1.0050x over previous
//
#include <hip/hip_runtime.h>
#include <stdint.h>

#define NN 100000
#define NE 1600000
#define NG 1000
#define FIN 128
#define DIM 32
#define NC 10

#define NBKT 512          // super-buckets over dst nodes
#define NPB 196           // nodes per bucket (512*196 = 100352 >= NN)
#define BCAP 4096         // edges per bucket (mean 3136 + <=196 pad, ~10 sigma headroom)
#define RND 2048          // edges per binning block
#define CURS 16           // cursor stride in ints (one per 64-B line)
#define NBINB 782         // binning blocks
#define NMM1 1563         // mm1 blocks (64 nodes each)
#define MM1P1 781         // mm1 blocks co-dispatched with bin
#define MM1P2 782         // mm1 blocks co-dispatched with csr
#define WP 36             // W pitch in shorts (8-B aligned rows, bank-conflict-free frag reads)

typedef unsigned int u32;
typedef __attribute__((ext_vector_type(8))) short short8;
typedef __attribute__((ext_vector_type(4))) float floatx4;
typedef __attribute__((ext_vector_type(4))) unsigned int uint4e;

__device__ __forceinline__ ushort f2bf(float f) {
    u32 b = __float_as_uint(f);
    return (ushort)((b + 0x7FFFu + ((b >> 16) & 1u)) >> 16);   // RNE
}
__device__ __forceinline__ float bf2f(ushort u) {
    return __uint_as_float(((u32)u) << 16);
}

// shared-memory union for the combined dispatches (max member 35.8 KB -> 4 blocks/CU)
union SMemU {
    struct {               // binning: 28.0 KB
        uint2  ent[RND];
        ushort bk16[RND];
        int cnt[NBKT]; int sA[NBKT]; int sB[NBKT]; int gbase[NBKT];
    } b;
    struct {               // csr: 34.4 KB
        uint2 ent[BCAP];
        int hist[NPB]; int sc[NPB]; int base[NPB];
    } c;
    struct {               // mm1: 17.4 + 9.2 + 9.2 = 35.8 KB
        ushort xs[64 * 136];
        ushort wrel[FIN * WP];
        ushort wroot[FIN * WP];
    } m;
};

// ---------------- zero ----------------
__global__ void k_zero(u32* __restrict__ p, int n) {
    int i = blockIdx.x * blockDim.x + threadIdx.x;
    if (i < n) p[i] = 0u;
}

// ---------------- bodies ----------------
__device__ void bin_body(SMemU& sm, int blk, const int* __restrict__ ei,
        const float* __restrict__ ew, int* __restrict__ cursor,
        uint2* __restrict__ ebuf) {
    int tid = threadIdx.x;
    int e0 = blk * RND;
    int n  = min(RND, NE - e0);

    for (int i = tid; i < NBKT; i += 256) sm.b.cnt[i] = 0;
    __syncthreads();

    u32 pk[8], wv[8], bp[8];
    #pragma unroll
    for (int q = 0; q < 8; ++q) {
        int i = tid + q * 256;
        pk[q] = 0; wv[q] = 0; bp[q] = 0;
        if (i < n) {
            int s = ei[e0 + i];
            int d = ei[NE + e0 + i];
            float w = ew[e0 + i];
            int b = d / NPB;
            int loc = d - b * NPB;
            int p = atomicAdd(&sm.b.cnt[b], 1);
            pk[q] = (u32)s | ((u32)loc << 17);
            wv[q] = __float_as_uint(w);
            bp[q] = (u32)p | ((u32)b << 16);
        }
    }
    __syncthreads();

    for (int i = tid; i < NBKT; i += 256) sm.b.sA[i] = sm.b.cnt[i];
    __syncthreads();
    int* ssrc = sm.b.sA; int* sdst = sm.b.sB;
    for (int dd = 1; dd < NBKT; dd <<= 1) {
        for (int i = tid; i < NBKT; i += 256)
            sdst[i] = ssrc[i] + (i >= dd ? ssrc[i - dd] : 0);
        __syncthreads();
        int* t = ssrc; ssrc = sdst; sdst = t;
    }
    for (int i = tid; i < NBKT; i += 256) {
        int excl = ssrc[i] - sm.b.cnt[i];
        sdst[i] = excl;
        if (sm.b.cnt[i] > 0) sm.b.gbase[i] = atomicAdd(&cursor[i * CURS], sm.b.cnt[i]);
    }
    __syncthreads();
    int* basep = sdst;

    #pragma unroll
    for (int q = 0; q < 8; ++q) {
        int i = tid + q * 256;
        if (i < n) {
            int b = (int)(bp[q] >> 16);
            int p = (int)(bp[q] & 0xFFFFu);
            int pos = basep[b] + p;
            sm.b.ent[pos]  = make_uint2(pk[q], wv[q]);
            sm.b.bk16[pos] = (ushort)b;
        }
    }
    __syncthreads();

    for (int i = tid; i < n; i += 256) {
        int b = (int)sm.b.bk16[i];
        int dsti = sm.b.gbase[b] + (i - basep[b]);
        if (dsti < BCAP) ebuf[(size_t)b * BCAP + dsti] = sm.b.ent[i];
    }
}

__device__ void csr_body(SMemU& sm, int bkt, uint2* __restrict__ ebuf,
        const int* __restrict__ cursor, uint2* __restrict__ od) {
    int tid = threadIdx.x;
    int cnt = min(cursor[bkt * CURS], BCAP);
    for (int i = tid; i < NPB; i += 256) sm.c.hist[i] = 0;
    __syncthreads();
    uint2* gb = ebuf + (size_t)bkt * BCAP;
    uint2 my[16]; int mp[16];
    #pragma unroll
    for (int q = 0; q < 16; ++q) {
        int i = tid + q * 256;
        mp[q] = -1;
        if (i < cnt) {
            my[q] = gb[i];
            int loc = (int)(my[q].x >> 17);
            mp[q] = atomicAdd(&sm.c.hist[loc], 1);
        }
    }
    __syncthreads();
    for (int i = tid; i < NPB; i += 256) sm.c.sc[i] = (sm.c.hist[i] + 1) & ~1;
    __syncthreads();
    for (int dd = 1; dd < NPB; dd <<= 1) {
        int v = 0;
        if (tid < NPB) { v = sm.c.sc[tid]; if (tid >= dd) v += sm.c.sc[tid - dd]; }
        __syncthreads();
        if (tid < NPB) sm.c.sc[tid] = v;
        __syncthreads();
    }
    for (int i = tid; i < NPB; i += 256) sm.c.base[i] = sm.c.sc[i] - ((sm.c.hist[i] + 1) & ~1);
    __syncthreads();
    int tot = min(sm.c.sc[NPB - 1], BCAP);
    for (int i = tid; i < tot; i += 256) sm.c.ent[i] = make_uint2(0u, 0u);
    __syncthreads();
    #pragma unroll
    for (int q = 0; q < 16; ++q) {
        if (mp[q] >= 0) {
            int loc = (int)(my[q].x >> 17);
            int pos = sm.c.base[loc] + mp[q];
            if (pos < BCAP) sm.c.ent[pos] = my[q];
        }
    }
    __syncthreads();
    for (int i = tid; i < tot; i += 256) gb[i] = sm.c.ent[i];
    for (int i = tid; i < NPB; i += 256) {
        int node = bkt * NPB + i;
        if (node < NN) {
            int dg = sm.c.hist[i];
            if (sm.c.base[i] + dg > BCAP) dg = max(0, BCAP - sm.c.base[i]);
            od[node] = make_uint2((u32)(bkt * BCAP + sm.c.base[i]), (u32)dg);
        }
    }
}

__device__ void mm1_body(SMemU& sm, int blk, const float* __restrict__ x,
        const float* __restrict__ Wrel, const float* __restrict__ brel,
        const float* __restrict__ Wroot,
        ushort* __restrict__ ybf, float* __restrict__ aggi) {
    int tid = threadIdx.x;
    int base = blk * 64;
    // stage W -> bf16 LDS, pitch WP shorts (coalesced float4 reads, 8-B aligned ushort4 writes)
    for (int i = tid; i < FIN * DIM / 4; i += 256) {
        int k = i >> 3, c = i & 7;
        float4 v1 = ((const float4*)Wrel)[i];
        float4 v2 = ((const float4*)Wroot)[i];
        ushort4 u1, u2;
        u1.x = f2bf(v1.x); u1.y = f2bf(v1.y); u1.z = f2bf(v1.z); u1.w = f2bf(v1.w);
        u2.x = f2bf(v2.x); u2.y = f2bf(v2.y); u2.z = f2bf(v2.z); u2.w = f2bf(v2.w);
        *(ushort4*)&sm.m.wrel[k * WP + c * 4]  = u1;
        *(ushort4*)&sm.m.wroot[k * WP + c * 4] = u2;
    }
    for (int i = tid; i < 64 * 32; i += 256) {
        int r = i >> 5, c = i & 31;
        int node = base + r;
        float4 v = make_float4(0.f, 0.f, 0.f, 0.f);
        if (node < NN) v = ((const float4*)x)[(size_t)node * 32 + c];
        ushort4 u;
        u.x = f2bf(v.x); u.y = f2bf(v.y); u.z = f2bf(v.z); u.w = f2bf(v.w);
        *(ushort4*)&sm.m.xs[r * 136 + c * 4] = u;
    }
    __syncthreads();
    int lane = tid & 63;
    int w = tid >> 6;
    int m = lane & 15;
    int q = lane >> 4;
    short8 bfr[4][4];
    #pragma unroll
    for (int nt = 0; nt < 4; ++nt) {
        const ushort* W = (nt < 2) ? sm.m.wrel : sm.m.wroot;
        int ncol = (nt & 1) * 16 + m;
        #pragma unroll
        for (int kc = 0; kc < 4; ++kc) {
            short8 fr;
            #pragma unroll
            for (int j = 0; j < 8; ++j)
                fr[j] = (short)W[(kc * 32 + q * 8 + j) * WP + ncol];
            bfr[nt][kc] = fr;
        }
    }
    floatx4 acc[4] = {{0.f,0.f,0.f,0.f},{0.f,0.f,0.f,0.f},{0.f,0.f,0.f,0.f},{0.f,0.f,0.f,0.f}};
    #pragma unroll
    for (int kc = 0; kc < 4; ++kc) {
        short8 af = *(const short8*)&sm.m.xs[(w * 16 + m) * 136 + kc * 32 + q * 8];
        #pragma unroll
        for (int nt = 0; nt < 4; ++nt)
            acc[nt] = __builtin_amdgcn_mfma_f32_16x16x32_bf16(af, bfr[nt][kc], acc[nt], 0, 0, 0);
    }
    float br0 = brel[m], br1 = brel[16 + m];
    #pragma unroll
    for (int reg = 0; reg < 4; ++reg) {
        int row = q * 4 + reg;
        int node = base + w * 16 + row;
        if (node < NN) {
            ybf[(size_t)node * 32 + m]       = f2bf(acc[0][reg]);
            ybf[(size_t)node * 32 + 16 + m]  = f2bf(acc[1][reg]);
            aggi[(size_t)node * 32 + m]      = acc[2][reg] + br0;
            aggi[(size_t)node * 32 + 16 + m] = acc[3][reg] + br1;
        }
    }
}

// ---------------- combined dispatches: bin || mm1-half1, csr || mm1-half2 ----------------
__global__ __launch_bounds__(256) void k_pre1(const int* __restrict__ ei,
        const float* __restrict__ ew, int* __restrict__ cursor, uint2* __restrict__ ebuf,
        const float* __restrict__ x, const float* __restrict__ Wrel,
        const float* __restrict__ brel, const float* __restrict__ Wroot,
        ushort* __restrict__ ybf, float* __restrict__ aggi) {
    __shared__ SMemU sm;
    if (blockIdx.x < NBINB) bin_body(sm, blockIdx.x, ei, ew, cursor, ebuf);
    else                    mm1_body(sm, blockIdx.x - NBINB, x, Wrel, brel, Wroot, ybf, aggi);
}

__global__ __launch_bounds__(256) void k_pre2(uint2* __restrict__ ebuf,
        const int* __restrict__ cursor, uint2* __restrict__ od,
        const float* __restrict__ x, const float* __restrict__ Wrel,
        const float* __restrict__ brel, const float* __restrict__ Wroot,
        ushort* __restrict__ ybf, float* __restrict__ aggi) {
    __shared__ SMemU sm;
    if (blockIdx.x < NBKT) csr_body(sm, blockIdx.x, ebuf, cursor, od);
    else                   mm1_body(sm, blockIdx.x - NBKT + MM1P1, x, Wrel, brel, Wroot, ybf, aggi);
}

// ---------------- fused gather + relu + next-layer dual matmul ----------------
__global__ __launch_bounds__(256, 6) void k_gfused(const ushort* __restrict__ ybf,
        const uint2* __restrict__ ebuf, const uint2* __restrict__ od,
        const float* __restrict__ aggi,
        const float* __restrict__ Wrel, const float* __restrict__ brel,
        const float* __restrict__ Wroot,
        ushort* __restrict__ ybf_n, float* __restrict__ aggi_n) {
    __shared__ float wr[DIM * DIM];
    __shared__ float wo[DIM * DIM];
    __shared__ float hsm[8][DIM + 1];
    int tid = threadIdx.x;
    for (int i = tid; i < DIM * DIM / 4; i += 256) {
        ((float4*)wr)[i] = ((const float4*)Wrel)[i];
        ((float4*)wo)[i] = ((const float4*)Wroot)[i];
    }
    int f = tid & 31;
    int ng = tid >> 5;
    int node = blockIdx.x * 8 + ng;           // grid*8 == NN exactly
    uint2 o = od[node];
    int deg = (int)o.y;
    const uint4e* eb4 = (const uint4e*)(ebuf + o.x);
    const ushort* yb = ybf + f;
    size_t oo = (size_t)node * DIM + f;
    float prev = __builtin_nontemporal_load(&aggi[oo]);
    float acc0 = 0.f, acc1 = 0.f;
    for (int b = 0; b < deg; b += 16) {
        const uint4e* p = eb4 + (b >> 1);
        uint4e e0 = __builtin_nontemporal_load(p + 0);
        uint4e e1 = __builtin_nontemporal_load(p + 1);
        uint4e e2 = __builtin_nontemporal_load(p + 2);
        uint4e e3 = __builtin_nontemporal_load(p + 3);
        uint4e e4 = __builtin_nontemporal_load(p + 4);
        uint4e e5 = __builtin_nontemporal_load(p + 5);
        uint4e e6 = __builtin_nontemporal_load(p + 6);
        uint4e e7 = __builtin_nontemporal_load(p + 7);
        float y0  = bf2f(yb[(size_t)(e0.x & 0x1FFFFu) * DIM]);
        float y1  = bf2f(yb[(size_t)(e0.z & 0x1FFFFu) * DIM]);
        float y2  = bf2f(yb[(size_t)(e1.x & 0x1FFFFu) * DIM]);
        float y3  = bf2f(yb[(size_t)(e1.z & 0x1FFFFu) * DIM]);
        float y4  = bf2f(yb[(size_t)(e2.x & 0x1FFFFu) * DIM]);
        float y5  = bf2f(yb[(size_t)(e2.z & 0x1FFFFu) * DIM]);
        float y6  = bf2f(yb[(size_t)(e3.x & 0x1FFFFu) * DIM]);
        float y7  = bf2f(yb[(size_t)(e3.z & 0x1FFFFu) * DIM]);
        float y8  = bf2f(yb[(size_t)(e4.x & 0x1FFFFu) * DIM]);
        float y9  = bf2f(yb[(size_t)(e4.z & 0x1FFFFu) * DIM]);
        float y10 = bf2f(yb[(size_t)(e5.x & 0x1FFFFu) * DIM]);
        float y11 = bf2f(yb[(size_t)(e5.z & 0x1FFFFu) * DIM]);
        float y12 = bf2f(yb[(size_t)(e6.x & 0x1FFFFu) * DIM]);
        float y13 = bf2f(yb[(size_t)(e6.z & 0x1FFFFu) * DIM]);
        float y14 = bf2f(yb[(size_t)(e7.x & 0x1FFFFu) * DIM]);
        float y15 = bf2f(yb[(size_t)(e7.z & 0x1FFFFu) * DIM]);
        int r = deg - b;
        acc0 += (( 0 < r) ? __uint_as_float(e0.y) : 0.f) * y0;
        acc1 += (( 1 < r) ? __uint_as_float(e0.w) : 0.f) * y1;
        acc0 += (( 2 < r) ? __uint_as_float(e1.y) : 0.f) * y2;
        acc1 += (( 3 < r) ? __uint_as_float(e1.w) : 0.f) * y3;
        acc0 += (( 4 < r) ? __uint_as_float(e2.y) : 0.f) * y4;
        acc1 += (( 5 < r) ? __uint_as_float(e2.w) : 0.f) * y5;
        acc0 += (( 6 < r) ? __uint_as_float(e3.y) : 0.f) * y6;
        acc1 += (( 7 < r) ? __uint_as_float(e3.w) : 0.f) * y7;
        acc0 += (( 8 < r) ? __uint_as_float(e4.y) : 0.f) * y8;
        acc1 += (( 9 < r) ? __uint_as_float(e4.w) : 0.f) * y9;
        acc0 += ((10 < r) ? __uint_as_float(e5.y) : 0.f) * y10;
        acc1 += ((11 < r) ? __uint_as_float(e5.w) : 0.f) * y11;
        acc0 += ((12 < r) ? __uint_as_float(e6.y) : 0.f) * y12;
        acc1 += ((13 < r) ? __uint_as_float(e6.w) : 0.f) * y13;
        acc0 += ((14 < r) ? __uint_as_float(e7.y) : 0.f) * y14;
        acc1 += ((15 < r) ? __uint_as_float(e7.w) : 0.f) * y15;
    }
    hsm[ng][f] = fmaxf(prev + acc0 + acc1, 0.f);
    __syncthreads();
    float ya = 0.f, aa = brel[f];
    #pragma unroll
    for (int k = 0; k < DIM; ++k) {
        float hv = hsm[ng][k];
        ya += hv * wr[k * DIM + f];
        aa += hv * wo[k * DIM + f];
    }
    ybf_n[oo] = f2bf(ya);
    __builtin_nontemporal_store(aa, &aggi_n[oo]);
}

// ---------------- fused last gather + relu + pool ----------------
__global__ __launch_bounds__(256, 6) void k_glast_pool(const ushort* __restrict__ ybf,
        const uint2* __restrict__ ebuf, const uint2* __restrict__ od,
        const float* __restrict__ aggi, const int* __restrict__ batch,
        float* __restrict__ g) {
    __shared__ float hsm[8][DIM + 1];
    int tid = threadIdx.x;
    int f = tid & 31;
    int ng = tid >> 5;
    int node = blockIdx.x * 8 + ng;           // grid*8 == NN exactly
    uint2 o = od[node];
    int deg = (int)o.y;
    const uint4e* eb4 = (const uint4e*)(ebuf + o.x);
    const ushort* yb = ybf + f;
    size_t oo = (size_t)node * DIM + f;
    float prev = __builtin_nontemporal_load(&aggi[oo]);
    float acc0 = 0.f, acc1 = 0.f;
    for (int b = 0; b < deg; b += 16) {
        const uint4e* p = eb4 + (b >> 1);
        uint4e e0 = __builtin_nontemporal_load(p + 0);
        uint4e e1 = __builtin_nontemporal_load(p + 1);
        uint4e e2 = __builtin_nontemporal_load(p + 2);
        uint4e e3 = __builtin_nontemporal_load(p + 3);
        uint4e e4 = __builtin_nontemporal_load(p + 4);
        uint4e e5 = __builtin_nontemporal_load(p + 5);
        uint4e e6 = __builtin_nontemporal_load(p + 6);
        uint4e e7 = __builtin_nontemporal_load(p + 7);
        float y0  = bf2f(yb[(size_t)(e0.x & 0x1FFFFu) * DIM]);
        float y1  = bf2f(yb[(size_t)(e0.z & 0x1FFFFu) * DIM]);
        float y2  = bf2f(yb[(size_t)(e1.x & 0x1FFFFu) * DIM]);
        float y3  = bf2f(yb[(size_t)(e1.z & 0x1FFFFu) * DIM]);
        float y4  = bf2f(yb[(size_t)(e2.x & 0x1FFFFu) * DIM]);
        float y5  = bf2f(yb[(size_t)(e2.z & 0x1FFFFu) * DIM]);
        float y6  = bf2f(yb[(size_t)(e3.x & 0x1FFFFu) * DIM]);
        float y7  = bf2f(yb[(size_t)(e3.z & 0x1FFFFu) * DIM]);
        float y8  = bf2f(yb[(size_t)(e4.x & 0x1FFFFu) * DIM]);
        float y9  = bf2f(yb[(size_t)(e4.z & 0x1FFFFu) * DIM]);
        float y10 = bf2f(yb[(size_t)(e5.x & 0x1FFFFu) * DIM]);
        float y11 = bf2f(yb[(size_t)(e5.z & 0x1FFFFu) * DIM]);
        float y12 = bf2f(yb[(size_t)(e6.x & 0x1FFFFu) * DIM]);
        float y13 = bf2f(yb[(size_t)(e6.z & 0x1FFFFu) * DIM]);
        float y14 = bf2f(yb[(size_t)(e7.x & 0x1FFFFu) * DIM]);
        float y15 = bf2f(yb[(size_t)(e7.z & 0x1FFFFu) * DIM]);
        int r = deg - b;
        acc0 += (( 0 < r) ? __uint_as_float(e0.y) : 0.f) * y0;
        acc1 += (( 1 < r) ? __uint_as_float(e0.w) : 0.f) * y1;
        acc0 += (( 2 < r) ? __uint_as_float(e1.y) : 0.f) * y2;
        acc1 += (( 3 < r) ? __uint_as_float(e1.w) : 0.f) * y3;
        acc0 += (( 4 < r) ? __uint_as_float(e2.y) : 0.f) * y4;
        acc1 += (( 5 < r) ? __uint_as_float(e2.w) : 0.f) * y5;
        acc0 += (( 6 < r) ? __uint_as_float(e3.y) : 0.f) * y6;
        acc1 += (( 7 < r) ? __uint_as_float(e3.w) : 0.f) * y7;
        acc0 += (( 8 < r) ? __uint_as_float(e4.y) : 0.f) * y8;
        acc1 += (( 9 < r) ? __uint_as_float(e4.w) : 0.f) * y9;
        acc0 += ((10 < r) ? __uint_as_float(e5.y) : 0.f) * y10;
        acc1 += ((11 < r) ? __uint_as_float(e5.w) : 0.f) * y11;
        acc0 += ((12 < r) ? __uint_as_float(e6.y) : 0.f) * y12;
        acc1 += ((13 < r) ? __uint_as_float(e6.w) : 0.f) * y13;
        acc0 += ((14 < r) ? __uint_as_float(e7.y) : 0.f) * y14;
        acc1 += ((15 < r) ? __uint_as_float(e7.w) : 0.f) * y15;
    }
    hsm[ng][f] = fmaxf(prev + acc0 + acc1, 0.f);
    __syncthreads();
    if (tid < 32) {                            // segmented sum over 8 sorted nodes
        int nb = blockIdx.x * 8;
        int curb = batch[nb];
        float run = 0.f;
        #pragma unroll
        for (int n = 0; n < 8; ++n) {
            int b = batch[nb + n];
            if (b != curb) {
                atomicAdd(&g[(size_t)curb * DIM + tid], run);
                run = 0.f; curb = b;
            }
            run += hsm[n][tid];
        }
        atomicAdd(&g[(size_t)curb * DIM + tid], run);
    }
}

// ---------------- head ----------------
__global__ __launch_bounds__(64) void k_head(const float* __restrict__ g,
        const float* __restrict__ W1, const float* __restrict__ b1,
        const float* __restrict__ W2, const float* __restrict__ b2,
        float* __restrict__ out) {
    __shared__ float gs[DIM];
    __shared__ float a1[DIM];
    __shared__ float lg[NC];
    int t = threadIdx.x;
    int gr = blockIdx.x;
    if (t < DIM) gs[t] = g[(size_t)gr * DIM + t];
    __syncthreads();
    if (t < DIM) {
        float a = b1[t];
        #pragma unroll
        for (int k = 0; k < DIM; ++k) a += gs[k] * W1[k * DIM + t];
        a1[t] = fmaxf(a, 0.f);
    }
    __syncthreads();
    if (t < NC) {
        float a = b2[t];
        #pragma unroll
        for (int k = 0; k < DIM; ++k) a += a1[k] * W2[k * NC + t];
        lg[t] = a;
    }
    __syncthreads();
    if (t == 0) {
        float m = lg[0];
        for (int c = 1; c < NC; ++c) m = fmaxf(m, lg[c]);
        float s = 0.f;
        for (int c = 0; c < NC; ++c) s += expf(lg[c] - m);
        float ls = m + logf(s);
        for (int c = 0; c < NC; ++c) out[(size_t)gr * NC + c] = lg[c] - ls;
    }
}

extern "C" void kernel_launch(void* const* d_in, const int* in_sizes, int n_in,
                              void* d_out, int out_size, void* d_ws, size_t ws_size,
                              hipStream_t stream) {
    const float* x     = (const float*)d_in[0];
    const int*   ei    = (const int*)d_in[1];
    const int*   batch = (const int*)d_in[2];
    const float* ew    = (const float*)d_in[3];
    const float* Wrel[5]  = {(const float*)d_in[4],  (const float*)d_in[7],  (const float*)d_in[10], (const float*)d_in[13], (const float*)d_in[16]};
    const float* brel[5]  = {(const float*)d_in[5],  (const float*)d_in[8],  (const float*)d_in[11], (const float*)d_in[14], (const float*)d_in[17]};
    const float* Wroot[5] = {(const float*)d_in[6],  (const float*)d_in[9],  (const float*)d_in[12], (const float*)d_in[15], (const float*)d_in[18]};
    const float* W1 = (const float*)d_in[19];
    const float* b1 = (const float*)d_in[20];
    const float* W2 = (const float*)d_in[21];
    const float* b2 = (const float*)d_in[22];
    float* out = (float*)d_out;

    char* ws = (char*)d_ws;
    const size_t off_cursor = 0;                                   // 32768
    const size_t off_g      = 32768;                               // 128000
    const size_t zero_end   = 160768;
    const size_t off_ebuf   = 160768;
    const size_t off_od     = off_ebuf + ((size_t)NBKT * BCAP + 64) * 8;
    const size_t off_A      = off_od + (size_t)NN * 8;             // aggi ping
    const size_t off_C      = off_A + (size_t)NN * DIM * 4;        // aggi pong
    const size_t off_B1     = off_C + (size_t)NN * DIM * 4;        // y ping (bf16)
    const size_t off_B2     = off_B1 + (size_t)NN * DIM * 2;       // y pong (bf16)
    const size_t need       = off_B2 + (size_t)NN * DIM * 2;       // ~56 MB
    if (ws_size < need) return;

    int*    cursor = (int*)(ws + off_cursor);
    float*  g      = (float*)(ws + off_g);
    uint2*  ebuf   = (uint2*)(ws + off_ebuf);
    uint2*  od     = (uint2*)(ws + off_od);
    float*  A      = (float*)(ws + off_A);
    float*  C      = (float*)(ws + off_C);
    ushort* B1     = (ushort*)(ws + off_B1);
    ushort* B2     = (ushort*)(ws + off_B2);

    int zcount = (int)(zero_end / 4);
    k_zero<<<(zcount + 255) / 256, 256, 0, stream>>>((u32*)ws, zcount);

    // combined: binning || mm1 first half, then csr || mm1 second half
    k_pre1<<<NBINB + MM1P1, 256, 0, stream>>>(ei, ew, cursor, ebuf,
                                              x, Wrel[0], brel[0], Wroot[0], B1, A);
    k_pre2<<<NBKT + MM1P2, 256, 0, stream>>>(ebuf, cursor, od,
                                             x, Wrel[0], brel[0], Wroot[0], B1, A);

    const int ngt = NN / 8;                    // 12500 (exact)
    float*  aggc = A;  float*  aggn = C;
    ushort* yc   = B1; ushort* yn   = B2;
    for (int L = 1; L < 5; ++L) {
        k_gfused<<<ngt, 256, 0, stream>>>(yc, ebuf, od, aggc,
                                          Wrel[L], brel[L], Wroot[L], yn, aggn);
        float* tf = aggc; aggc = aggn; aggn = tf;
        ushort* tu = yc; yc = yn; yn = tu;
    }
    k_glast_pool<<<ngt, 256, 0, stream>>>(yc, ebuf, od, aggc, batch, g);
    k_head<<<NG, 64, 0, stream>>>(g, W1, b1, W2, b2, out);
}